// Round 1
// baseline (596.338 us; speedup 1.0000x reference)
//
#include <hip/hip_runtime.h>
#include <math.h>

#define B_ 2
#define L_ 2048
#define D_ 512
#define H_ 8
#define DH 64
#define NS 2048   // U_part (sampled keys)
#define NU 40     // u (selected queries)
#define BHD (L_*D_)        // 1048576: per-batch stride of qp/kp/vp
#define QHS (L_*DH)        // 131072: per-head stride inside qh view

__device__ inline float4 ld4(const float* p) { return *reinterpret_cast<const float4*>(p); }

// ---------------------------------------------------------------- GEMM: C = A @ W^T + bias
// A: M x 512, W: 512 x 512 (row-major, k-contiguous for both), C: M x 512
__global__ __launch_bounds__(256) void gemm_xwT(const float* __restrict__ A,
                                                const float* __restrict__ W,
                                                const float* __restrict__ bias,
                                                float* __restrict__ C, int M) {
  __shared__ float a_t[128][33];
  __shared__ float w_t[128][33];
  const int t  = threadIdx.x;
  const int ty = t >> 4, tx = t & 15;
  const int m0 = blockIdx.x * 128, n0 = blockIdx.y * 128;
  float acc[8][8];
#pragma unroll
  for (int i = 0; i < 8; ++i)
#pragma unroll
    for (int j = 0; j < 8; ++j) acc[i][j] = 0.f;

  const int srow = t >> 1;          // 0..127
  const int scb  = (t & 1) * 16;    // float offset within 32-float k-chunk

  for (int k0 = 0; k0 < 512; k0 += 32) {
    __syncthreads();
    {
      const int gm = m0 + srow;
      const float* src  = A + (size_t)gm * 512 + k0 + scb;
      const float* wsrc = W + (size_t)(n0 + srow) * 512 + k0 + scb;
#pragma unroll
      for (int i = 0; i < 4; ++i) {
        float4 v = (gm < M) ? ld4(src + 4*i) : make_float4(0.f, 0.f, 0.f, 0.f);
        a_t[srow][scb + 4*i + 0] = v.x;
        a_t[srow][scb + 4*i + 1] = v.y;
        a_t[srow][scb + 4*i + 2] = v.z;
        a_t[srow][scb + 4*i + 3] = v.w;
      }
#pragma unroll
      for (int i = 0; i < 4; ++i) {
        float4 v = ld4(wsrc + 4*i);
        w_t[srow][scb + 4*i + 0] = v.x;
        w_t[srow][scb + 4*i + 1] = v.y;
        w_t[srow][scb + 4*i + 2] = v.z;
        w_t[srow][scb + 4*i + 3] = v.w;
      }
    }
    __syncthreads();
#pragma unroll 4
    for (int kk = 0; kk < 32; ++kk) {
      float av[8], wv[8];
#pragma unroll
      for (int i = 0; i < 8; ++i) av[i] = a_t[ty + 16*i][kk];
#pragma unroll
      for (int i = 0; i < 8; ++i) wv[i] = w_t[tx + 16*i][kk];
#pragma unroll
      for (int i = 0; i < 8; ++i)
#pragma unroll
        for (int j = 0; j < 8; ++j) acc[i][j] += av[i] * wv[j];
    }
  }
#pragma unroll
  for (int i = 0; i < 8; ++i) {
    const int gm = m0 + ty + 16*i;
    if (gm < M) {
#pragma unroll
      for (int j = 0; j < 8; ++j) {
        const int gn = n0 + tx + 16*j;
        C[(size_t)gm*512 + gn] = acc[i][j] + bias[gn];
      }
    }
  }
}

// ---------------------------------------------------------------- Ksum[bh][j] = sum_s kp[b, idx[s], h*64+j]
__global__ __launch_bounds__(1024) void ksum_kernel(const float* __restrict__ kp,
                                                    const int* __restrict__ idx,
                                                    float* __restrict__ ksum) {
  __shared__ float part[16][64];
  const int bh = blockIdx.x;
  const int b = bh >> 3, h = bh & 7;
  const int t = threadIdx.x;
  const int sg = t >> 6, j = t & 63;
  const float* kbase = kp + (size_t)b*BHD + h*DH;
  float a = 0.f;
  for (int s = sg*128; s < sg*128 + 128; ++s)
    a += kbase[(size_t)idx[s]*512 + j];
  part[sg][j] = a;
  __syncthreads();
  if (t < 64) {
    float s = 0.f;
#pragma unroll
    for (int i = 0; i < 16; ++i) s += part[i][t];
    ksum[bh*64 + t] = s;
  }
}

// ---------------------------------------------------------------- M[bh][q] = max_s(q.k_idx[s]) - (q.Ksum)/2048
// grid: 512 blocks (bh = bid>>5, qtile = bid&31 of 64 queries); block 256
__global__ __launch_bounds__(256) void m_kernel(const float* __restrict__ qp,
                                                const float* __restrict__ kp,
                                                const int* __restrict__ idx,
                                                const float* __restrict__ ksum,
                                                float* __restrict__ Mout) {
  __shared__ float q_t[64][65];
  __shared__ float k_t[128][65];
  __shared__ float ks_s[64];
  const int t  = threadIdx.x;
  const int ty = t >> 4, tx = t & 15;
  const int bh = blockIdx.x >> 5, qt = blockIdx.x & 31;
  const int b = bh >> 3, h = bh & 7;

  {  // stage 64 queries (contiguous chunk thanks to the reshape trick)
    const float* qbase = qp + (size_t)b*BHD + (size_t)h*QHS + qt*64*64;
    const int row = t >> 2, cb = (t & 3)*16;
    const float* src = qbase + row*64 + cb;
#pragma unroll
    for (int i = 0; i < 4; ++i) {
      float4 v = ld4(src + 4*i);
      q_t[row][cb + 4*i + 0] = v.x;
      q_t[row][cb + 4*i + 1] = v.y;
      q_t[row][cb + 4*i + 2] = v.z;
      q_t[row][cb + 4*i + 3] = v.w;
    }
  }
  if (t < 64) ks_s[t] = ksum[bh*64 + t];

  float mx[4] = {-INFINITY, -INFINITY, -INFINITY, -INFINITY};
  const float* kbase = kp + (size_t)b*BHD + h*DH;
  const int krow = t >> 1, kcb = (t & 1)*32;

  for (int s0 = 0; s0 < NS; s0 += 128) {
    __syncthreads();
    {  // gather-stage 128 sampled K rows
      const int kidx = idx[s0 + krow];
      const float* src = kbase + (size_t)kidx*512 + kcb;
#pragma unroll
      for (int i = 0; i < 8; ++i) {
        float4 v = ld4(src + 4*i);
        k_t[krow][kcb + 4*i + 0] = v.x;
        k_t[krow][kcb + 4*i + 1] = v.y;
        k_t[krow][kcb + 4*i + 2] = v.z;
        k_t[krow][kcb + 4*i + 3] = v.w;
      }
    }
    __syncthreads();
    float acc[4][8];
#pragma unroll
    for (int i = 0; i < 4; ++i)
#pragma unroll
      for (int ii = 0; ii < 8; ++ii) acc[i][ii] = 0.f;
#pragma unroll 4
    for (int j = 0; j < 64; ++j) {
      float qv[4], kv[8];
#pragma unroll
      for (int i = 0; i < 4; ++i)  qv[i]  = q_t[ty + 16*i][j];
#pragma unroll
      for (int ii = 0; ii < 8; ++ii) kv[ii] = k_t[tx + 16*ii][j];
#pragma unroll
      for (int i = 0; i < 4; ++i)
#pragma unroll
        for (int ii = 0; ii < 8; ++ii) acc[i][ii] += qv[i]*kv[ii];
    }
#pragma unroll
    for (int i = 0; i < 4; ++i)
#pragma unroll
      for (int ii = 0; ii < 8; ++ii) mx[i] = fmaxf(mx[i], acc[i][ii]);
  }

  __syncthreads();
  float* red = &k_t[0][0];  // reuse as [64][17]
#pragma unroll
  for (int i = 0; i < 4; ++i) red[(ty + 16*i)*17 + tx] = mx[i];
  __syncthreads();
  if (t < 64) {
    float m = red[t*17];
#pragma unroll
    for (int c = 1; c < 16; ++c) m = fmaxf(m, red[t*17 + c]);
    float dot = 0.f;
#pragma unroll 8
    for (int j = 0; j < 64; ++j) dot += q_t[t][j]*ks_s[j];
    Mout[bh*L_ + qt*64 + t] = m - dot * (1.0f/2048.0f);
  }
}

// ---------------------------------------------------------------- top-40 smallest M, stable order (== top_k(-M))
__global__ __launch_bounds__(256) void topk_kernel(const float* __restrict__ Mout,
                                                   int* __restrict__ Mtop) {
  __shared__ float mv[2048];
  __shared__ float rv[256];
  __shared__ int   ri[256];
  const int bh = blockIdx.x;
  const int t = threadIdx.x;
#pragma unroll
  for (int c = 0; c < 8; ++c) mv[t + 256*c] = Mout[bh*L_ + t + 256*c];
  __syncthreads();
  for (int it = 0; it < NU; ++it) {
    float bv = mv[t]; int bi = t;
#pragma unroll
    for (int c = 1; c < 8; ++c) {
      const float v = mv[t + 256*c];
      if (v < bv) { bv = v; bi = t + 256*c; }   // ascending scan: strict < keeps lower index on tie
    }
    rv[t] = bv; ri[t] = bi;
    __syncthreads();
    for (int s = 128; s > 0; s >>= 1) {
      if (t < s) {
        const float v2 = rv[t+s]; const int i2 = ri[t+s];
        if (v2 < rv[t] || (v2 == rv[t] && i2 < ri[t])) { rv[t] = v2; ri[t] = i2; }
      }
      __syncthreads();
    }
    if (t == 0) { Mtop[bh*NU + it] = ri[0]; mv[ri[0]] = INFINITY; }
    __syncthreads();
  }
}

// ---------------------------------------------------------------- flash partials over 128-key slabs
// grid 256: bh = bid>>4, kt = bid&15. block 256: (g = t>>6, j = t&63); thread owns rows g*10..g*10+9, col j
__global__ __launch_bounds__(256) void flash_partial(const float* __restrict__ qp,
                                                     const float* __restrict__ kp,
                                                     const float* __restrict__ vp,
                                                     const int* __restrict__ Mtop,
                                                     float* __restrict__ pm,
                                                     float* __restrict__ pl,
                                                     float* __restrict__ pacc) {
  __shared__ float qr[NU][65];
  __shared__ float kv[64][65];
  __shared__ float sl[NU][65];
  __shared__ float ms[NU], ls[NU], fs[NU];
  const int bid = blockIdx.x;
  const int bh = bid >> 4, kt = bid & 15;
  const int b = bh >> 3, h = bh & 7;
  const int t = threadIdx.x;
  const int g = t >> 6, j = t & 63;

  {  // stage the 40 selected queries
    const float* qbase = qp + (size_t)b*BHD + (size_t)h*QHS;
#pragma unroll
    for (int r = 0; r < 10; ++r) {
      const int q = g*10 + r;
      qr[q][j] = qbase[(size_t)Mtop[bh*NU + q]*64 + j];
    }
  }
  if (t < NU) { ms[t] = -INFINITY; ls[t] = 0.f; }
  float acc[10];
#pragma unroll
  for (int r = 0; r < 10; ++r) acc[r] = 0.f;

  const float* kbase = kp + (size_t)b*BHD + h*DH;
  const float* vbase = vp + (size_t)b*BHD + h*DH;
  const int srow = t >> 2, scb = (t & 3)*16;

  for (int st = 0; st < 2; ++st) {
    const int kb = kt*128 + st*64;
    __syncthreads();                       // prior PV reads of kv/sl done
    {  // stage K tile (64x64)
      const float* src = kbase + (size_t)(kb + srow)*512 + scb;
#pragma unroll
      for (int i = 0; i < 4; ++i) {
        float4 v = ld4(src + 4*i);
        kv[srow][scb + 4*i + 0] = v.x;
        kv[srow][scb + 4*i + 1] = v.y;
        kv[srow][scb + 4*i + 2] = v.z;
        kv[srow][scb + 4*i + 3] = v.w;
      }
    }
    __syncthreads();
    {  // S = Qr . K^T * 0.125 -> sl
      float sv[10];
#pragma unroll
      for (int r = 0; r < 10; ++r) {
        const int q = g*10 + r;
        float s = 0.f;
#pragma unroll 8
        for (int jj = 0; jj < 64; ++jj) s += qr[q][jj]*kv[j][jj];
        sv[r] = s * 0.125f;
      }
#pragma unroll
      for (int r = 0; r < 10; ++r) sl[g*10 + r][j] = sv[r];
    }
    __syncthreads();
    // issue V loads into regs (overlaps the row stats below)
    float4 vst[4];
    {
      const float* src = vbase + (size_t)(kb + srow)*512 + scb;
#pragma unroll
      for (int i = 0; i < 4; ++i) vst[i] = ld4(src + 4*i);
    }
    if (t < NU) {  // per-row running max + rescale factor
      float tm = sl[t][0];
      for (int kk = 1; kk < 64; ++kk) tm = fmaxf(tm, sl[t][kk]);
      const float nm = fmaxf(ms[t], tm);
      fs[t] = expf(ms[t] - nm);
      ms[t] = nm;
    }
    __syncthreads();
    {  // rescale acc, exponentiate scores in-place, stage V into kv
#pragma unroll
      for (int r = 0; r < 10; ++r) {
        const int q = g*10 + r;
        acc[r] *= fs[q];
        sl[q][j] = expf(sl[q][j] - ms[q]);
      }
#pragma unroll
      for (int i = 0; i < 4; ++i) {
        kv[srow][scb + 4*i + 0] = vst[i].x;
        kv[srow][scb + 4*i + 1] = vst[i].y;
        kv[srow][scb + 4*i + 2] = vst[i].z;
        kv[srow][scb + 4*i + 3] = vst[i].w;
      }
    }
    __syncthreads();
    if (t < NU) {  // l update
      float sum = 0.f;
      for (int kk = 0; kk < 64; ++kk) sum += sl[t][kk];
      ls[t] = ls[t]*fs[t] + sum;
    }
    {  // PV accumulate
#pragma unroll 4
      for (int kk = 0; kk < 64; ++kk) {
        const float vv = kv[kk][j];
#pragma unroll
        for (int r = 0; r < 10; ++r) acc[r] += sl[g*10 + r][kk]*vv;
      }
    }
  }
  __syncthreads();
  const size_t base = (size_t)(bh*16 + kt)*NU;
  if (t < NU) { pm[base + t] = ms[t]; pl[base + t] = ls[t]; }
#pragma unroll
  for (int r = 0; r < 10; ++r)
    pacc[(base + g*10 + r)*64 + j] = acc[r];
}

// ---------------------------------------------------------------- combine 16 partials, write outc (B,40,512)
__global__ __launch_bounds__(256) void flash_combine(const float* __restrict__ pm,
                                                     const float* __restrict__ pl,
                                                     const float* __restrict__ pacc,
                                                     float* __restrict__ outc) {
  const int t = threadIdx.x;
  const int qg = t >> 6, j = t & 63;
  const int bh = blockIdx.x / 10;
  const int q  = (blockIdx.x % 10)*4 + qg;
  const int b = bh >> 3, h = bh & 7;
  float m = -INFINITY;
#pragma unroll
  for (int kt = 0; kt < 16; ++kt) m = fmaxf(m, pm[(size_t)(bh*16 + kt)*NU + q]);
  float Lsum = 0.f, num = 0.f;
#pragma unroll
  for (int kt = 0; kt < 16; ++kt) {
    const size_t base = (size_t)(bh*16 + kt)*NU;
    const float w = expf(pm[base + q] - m);
    Lsum += w * pl[base + q];
    num  += w * pacc[(base + q)*64 + j];
  }
  outc[(size_t)(b*NU + q)*512 + h*64 + j] = num / Lsum;
}

// ----------------------------------------------------------------
extern "C" void kernel_launch(void* const* d_in, const int* in_sizes, int n_in,
                              void* d_out, int out_size, void* d_ws, size_t ws_size,
                              hipStream_t stream) {
  const float* q  = (const float*)d_in[0];
  const float* k  = (const float*)d_in[1];
  const float* v  = (const float*)d_in[2];
  const float* Wq = (const float*)d_in[3];
  const float* bq = (const float*)d_in[4];
  const float* Wk = (const float*)d_in[5];
  const float* bk = (const float*)d_in[6];
  const float* Wv = (const float*)d_in[7];
  const float* bv = (const float*)d_in[8];
  const float* Wo = (const float*)d_in[9];
  const float* bo = (const float*)d_in[10];
  const int*  idx = (const int*)d_in[11];

  float* ws   = (float*)d_ws;
  float* qp   = ws;                       // 2,097,152
  float* kp   = ws + 2097152;             // 2,097,152
  float* vp   = ws + 4194304;             // 2,097,152
  float* ksum = ws + 6291456;             // 1,024
  float* Mout = ws + 6292480;             // 32,768
  int*   Mtop = (int*)(ws + 6325248);     // 640
  float* pm   = ws + 6325888;             // 10,240
  float* pl   = ws + 6336128;             // 10,240
  float* pacc = ws + 6346368;             // 655,360
  float* outc = ws + 7001728;             // 40,960

  const dim3 blk(256);
  gemm_xwT<<<dim3(32, 4), blk, 0, stream>>>(q, Wq, bq, qp, 4096);
  gemm_xwT<<<dim3(32, 4), blk, 0, stream>>>(k, Wk, bk, kp, 4096);
  gemm_xwT<<<dim3(32, 4), blk, 0, stream>>>(v, Wv, bv, vp, 4096);
  ksum_kernel<<<dim3(16), dim3(1024), 0, stream>>>(kp, idx, ksum);
  m_kernel<<<dim3(512), blk, 0, stream>>>(qp, kp, idx, ksum, Mout);
  topk_kernel<<<dim3(16), blk, 0, stream>>>(Mout, Mtop);
  flash_partial<<<dim3(256), blk, 0, stream>>>(qp, kp, vp, Mtop, pm, pl, pacc);
  flash_combine<<<dim3(160), blk, 0, stream>>>(pm, pl, pacc, outc);
  gemm_xwT<<<dim3(1, 4), blk, 0, stream>>>(outc, Wo, bo, (float*)d_out, 80);
}

// Round 2
// 369.426 us; speedup vs baseline: 1.6142x; 1.6142x over previous
//
#include <hip/hip_runtime.h>
#include <math.h>

#define B_ 2
#define L_ 2048
#define D_ 512
#define H_ 8
#define DH 64
#define NS 2048   // U_part (sampled keys)
#define NU 40     // u (selected queries)
#define BHD (L_*D_)        // per-batch stride of qp/kp/vp
#define QHS (L_*DH)        // per-head stride inside qh view

__device__ inline float4 ld4(const float* p) { return *reinterpret_cast<const float4*>(p); }

// ---------------------------------------------------------------- fused projection GEMM
// C = A @ W^T ; kh=0: C = acc + bias (K 0..255), kh=1: C += acc (K 256..511)
// grid (32 mtiles, 4 ntiles, 3 mats), 256 threads, 128x128 tile, 8x8 micro, BK=32
__global__ __launch_bounds__(256) void proj_gemm(
    const float* __restrict__ qa, const float* __restrict__ ka, const float* __restrict__ va,
    const float* __restrict__ Wq, const float* __restrict__ Wk, const float* __restrict__ Wv,
    const float* __restrict__ bq, const float* __restrict__ bk, const float* __restrict__ bv,
    float* __restrict__ qp, float* __restrict__ kp, float* __restrict__ vp, int kh)
{
  __shared__ __align__(16) float a_t[128][36];
  __shared__ __align__(16) float w_t[128][36];
  const int t = threadIdx.x;
  const int ty = t >> 4, tx = t & 15;
  const int mat = blockIdx.z;
  const float* A    = (mat == 0) ? qa : (mat == 1) ? ka : va;
  const float* W    = (mat == 0) ? Wq : (mat == 1) ? Wk : Wv;
  const float* bias = (mat == 0) ? bq : (mat == 1) ? bk : bv;
  float* C          = (mat == 0) ? qp : (mat == 1) ? kp : vp;
  const int m0 = blockIdx.x * 128, n0 = blockIdx.y * 128;
  const int srow = t >> 3, scol = (t & 7) * 4;   // 32 rows/pass, 4 passes

  float acc[8][8];
#pragma unroll
  for (int i = 0; i < 8; ++i)
#pragma unroll
    for (int j = 0; j < 8; ++j) acc[i][j] = 0.f;

  for (int c = 0; c < 8; ++c) {
    const int kb = kh * 256 + c * 32;
    __syncthreads();
#pragma unroll
    for (int i = 0; i < 4; ++i) {
      const int row = srow + 32 * i;
      *reinterpret_cast<float4*>(&a_t[row][scol]) = ld4(A + (size_t)(m0 + row) * 512 + kb + scol);
      *reinterpret_cast<float4*>(&w_t[row][scol]) = ld4(W + (size_t)(n0 + row) * 512 + kb + scol);
    }
    __syncthreads();
    for (int g = 0; g < 8; ++g) {
      float4 av[8], wv[8];
#pragma unroll
      for (int i = 0; i < 8; ++i) av[i] = *reinterpret_cast<const float4*>(&a_t[ty + 16 * i][4 * g]);
#pragma unroll
      for (int j = 0; j < 8; ++j) wv[j] = *reinterpret_cast<const float4*>(&w_t[tx + 16 * j][4 * g]);
#pragma unroll
      for (int i = 0; i < 8; ++i)
#pragma unroll
        for (int j = 0; j < 8; ++j) {
          acc[i][j] += av[i].x * wv[j].x;
          acc[i][j] += av[i].y * wv[j].y;
          acc[i][j] += av[i].z * wv[j].z;
          acc[i][j] += av[i].w * wv[j].w;
        }
    }
  }
#pragma unroll
  for (int i = 0; i < 8; ++i) {
    const int gm = m0 + ty + 16 * i;
#pragma unroll
    for (int j = 0; j < 8; ++j) {
      const int gn = n0 + tx + 16 * j;
      if (kh == 0) C[(size_t)gm * 512 + gn] = acc[i][j] + bias[gn];
      else         C[(size_t)gm * 512 + gn] += acc[i][j];
    }
  }
}

// ---------------------------------------------------------------- Ksum[bh][j] = sum_s kp[b, idx[s], h*64+j]
__global__ __launch_bounds__(1024) void ksum_kernel(const float* __restrict__ kp,
                                                    const int* __restrict__ idx,
                                                    float* __restrict__ ksum) {
  __shared__ float part[16][64];
  const int bh = blockIdx.x;
  const int b = bh >> 3, h = bh & 7;
  const int t = threadIdx.x;
  const int sg = t >> 6, j = t & 63;
  const float* kbase = kp + (size_t)b*BHD + h*DH;
  float a = 0.f;
  for (int s = sg*128; s < sg*128 + 128; ++s)
    a += kbase[(size_t)idx[s]*512 + j];
  part[sg][j] = a;
  __syncthreads();
  if (t < 64) {
    float s = 0.f;
#pragma unroll
    for (int i = 0; i < 16; ++i) s += part[i][t];
    ksum[bh*64 + t] = s;
  }
}

// ---------------------------------------------------------------- Mp[ks][bh][q] = max over 1024 sampled keys of q.k
// grid 512: bh=bid>>5, qt=(bid>>1)&15 (128-query tiles), ks=bid&1 (key half). 256 thr, 8x8 micro.
__global__ __launch_bounds__(256) void m_kernel(const float* __restrict__ qp,
                                                const float* __restrict__ kp,
                                                const int* __restrict__ idx,
                                                float* __restrict__ Mp) {
  __shared__ __align__(16) float q_t[128][68];
  __shared__ __align__(16) float k_t[128][36];
  const int t = threadIdx.x;
  const int ty = t >> 4, tx = t & 15;
  const int bid = blockIdx.x;
  const int bh = bid >> 5, qt = (bid >> 1) & 15, ks = bid & 1;
  const int b = bh >> 3, h = bh & 7;

  {  // stage 128 queries (contiguous chunk thanks to the reshape trick), full 64-wide
    const float* qbase = qp + (size_t)b*BHD + (size_t)h*QHS + qt*128*64;
    const int row0 = t >> 4, col = (t & 15) * 4;
#pragma unroll
    for (int i = 0; i < 8; ++i) {
      const int row = row0 + 16 * i;
      *reinterpret_cast<float4*>(&q_t[row][col]) = ld4(qbase + row * 64 + col);
    }
  }

  const float* kbase = kp + (size_t)b*BHD + h*DH;
  const int ib = ks * 1024;
  const int krow0 = t >> 3, kcol = (t & 7) * 4;

  float mx[8];
#pragma unroll
  for (int i = 0; i < 8; ++i) mx[i] = -INFINITY;

  for (int tile = 0; tile < 8; ++tile) {
    float acc[8][8];
#pragma unroll
    for (int i = 0; i < 8; ++i)
#pragma unroll
      for (int j = 0; j < 8; ++j) acc[i][j] = 0.f;

    for (int dc = 0; dc < 2; ++dc) {
      __syncthreads();
#pragma unroll
      for (int i = 0; i < 4; ++i) {
        const int row = krow0 + 32 * i;
        const int kidx = idx[ib + tile * 128 + row];
        *reinterpret_cast<float4*>(&k_t[row][kcol]) = ld4(kbase + (size_t)kidx * 512 + dc * 32 + kcol);
      }
      __syncthreads();
      for (int g = 0; g < 8; ++g) {
        float4 qv[8], kv[8];
#pragma unroll
        for (int i = 0; i < 8; ++i) qv[i] = *reinterpret_cast<const float4*>(&q_t[ty + 16 * i][dc * 32 + 4 * g]);
#pragma unroll
        for (int j = 0; j < 8; ++j) kv[j] = *reinterpret_cast<const float4*>(&k_t[tx + 16 * j][4 * g]);
#pragma unroll
        for (int i = 0; i < 8; ++i)
#pragma unroll
          for (int j = 0; j < 8; ++j) {
            acc[i][j] += qv[i].x * kv[j].x;
            acc[i][j] += qv[i].y * kv[j].y;
            acc[i][j] += qv[i].z * kv[j].z;
            acc[i][j] += qv[i].w * kv[j].w;
          }
      }
    }
#pragma unroll
    for (int i = 0; i < 8; ++i) {
      float m1 = acc[i][0];
#pragma unroll
      for (int j = 1; j < 8; ++j) m1 = fmaxf(m1, acc[i][j]);
      mx[i] = fmaxf(mx[i], m1);
    }
  }

  // reduce across the 16 tx lanes (max is order-independent)
#pragma unroll
  for (int i = 0; i < 8; ++i) {
    mx[i] = fmaxf(mx[i], __shfl_xor(mx[i], 1));
    mx[i] = fmaxf(mx[i], __shfl_xor(mx[i], 2));
    mx[i] = fmaxf(mx[i], __shfl_xor(mx[i], 4));
    mx[i] = fmaxf(mx[i], __shfl_xor(mx[i], 8));
  }
  if (tx == 0) {
#pragma unroll
    for (int i = 0; i < 8; ++i)
      Mp[ks * 32768 + bh * 2048 + qt * 128 + ty + 16 * i] = mx[i];
  }
}

// ---------------------------------------------------------------- fused M-finalize + top-40 (stable, == top_k(-M))
__global__ __launch_bounds__(256) void topk_kernel(const float* __restrict__ qp,
                                                   const float* __restrict__ ksum,
                                                   const float* __restrict__ Mp,
                                                   int* __restrict__ Mtop) {
  __shared__ float mv[2048];
  __shared__ float ks_s[64];
  __shared__ float wvs[4];
  __shared__ int   wis[4];
  const int bh = blockIdx.x;
  const int b = bh >> 3, h = bh & 7;
  const int t = threadIdx.x;
  if (t < 64) ks_s[t] = ksum[bh*64 + t];
  __syncthreads();
#pragma unroll
  for (int c = 0; c < 8; ++c) {
    const int qi = c * 256 + t;
    const float* qrow = qp + (size_t)b*BHD + (size_t)h*QHS + (size_t)qi * 64;
    float dot = 0.f;
#pragma unroll
    for (int cc = 0; cc < 16; ++cc) {          // same sequential j-order as before
      float4 q4 = ld4(qrow + 4 * cc);
      dot += q4.x * ks_s[4*cc + 0];
      dot += q4.y * ks_s[4*cc + 1];
      dot += q4.z * ks_s[4*cc + 2];
      dot += q4.w * ks_s[4*cc + 3];
    }
    mv[qi] = fmaxf(Mp[bh*2048 + qi], Mp[32768 + bh*2048 + qi]) - dot * (1.0f/2048.0f);
  }
  __syncthreads();
  const int wl = t & 63, w = t >> 6;
  for (int it = 0; it < NU; ++it) {
    float bv = mv[t]; int bi = t;
#pragma unroll
    for (int c = 1; c < 8; ++c) {
      const float v = mv[t + 256*c];
      if (v < bv) { bv = v; bi = t + 256*c; }   // ascending scan: strict < keeps lower index on tie
    }
#pragma unroll
    for (int off = 1; off < 64; off <<= 1) {
      const float ov = __shfl_xor(bv, off);
      const int   oi = __shfl_xor(bi, off);
      if (ov < bv || (ov == bv && oi < bi)) { bv = ov; bi = oi; }
    }
    if (wl == 0) { wvs[w] = bv; wis[w] = bi; }
    __syncthreads();
    if (t == 0) {
      float fv = wvs[0]; int fi = wis[0];
#pragma unroll
      for (int w2 = 1; w2 < 4; ++w2)
        if (wvs[w2] < fv || (wvs[w2] == fv && wis[w2] < fi)) { fv = wvs[w2]; fi = wis[w2]; }
      Mtop[bh*NU + it] = fi;
      mv[fi] = INFINITY;
    }
    __syncthreads();
  }
}

// ---------------------------------------------------------------- flash partials over 128-key slabs
__global__ __launch_bounds__(256) void flash_partial(const float* __restrict__ qp,
                                                     const float* __restrict__ kp,
                                                     const float* __restrict__ vp,
                                                     const int* __restrict__ Mtop,
                                                     float* __restrict__ pm,
                                                     float* __restrict__ pl,
                                                     float* __restrict__ pacc) {
  __shared__ float qr[NU][65];
  __shared__ float kv[64][65];
  __shared__ float sl[NU][65];
  __shared__ float ms[NU], ls[NU], fs[NU];
  const int bid = blockIdx.x;
  const int bh = bid >> 4, kt = bid & 15;
  const int b = bh >> 3, h = bh & 7;
  const int t = threadIdx.x;
  const int g = t >> 6, j = t & 63;
  const int r4 = t >> 2, sub = t & 3;   // quad-per-row mapping for row stats

  {  // stage the 40 selected queries
    const float* qbase = qp + (size_t)b*BHD + (size_t)h*QHS;
#pragma unroll
    for (int r = 0; r < 10; ++r) {
      const int q = g*10 + r;
      qr[q][j] = qbase[(size_t)Mtop[bh*NU + q]*64 + j];
    }
  }
  if (t < NU) { ms[t] = -INFINITY; ls[t] = 0.f; }
  float acc[10];
#pragma unroll
  for (int r = 0; r < 10; ++r) acc[r] = 0.f;

  const float* kbase = kp + (size_t)b*BHD + h*DH;
  const float* vbase = vp + (size_t)b*BHD + h*DH;
  const int srow = t >> 2, scb = (t & 3)*16;

  for (int st = 0; st < 2; ++st) {
    const int kb = kt*128 + st*64;
    __syncthreads();                       // prior PV reads of kv/sl done
    {  // stage K tile (64x64)
      const float* src = kbase + (size_t)(kb + srow)*512 + scb;
#pragma unroll
      for (int i = 0; i < 4; ++i) {
        float4 v = ld4(src + 4*i);
        kv[srow][scb + 4*i + 0] = v.x;
        kv[srow][scb + 4*i + 1] = v.y;
        kv[srow][scb + 4*i + 2] = v.z;
        kv[srow][scb + 4*i + 3] = v.w;
      }
    }
    __syncthreads();
    {  // S = Qr . K^T * 0.125 -> sl
      float sv[10];
#pragma unroll
      for (int r = 0; r < 10; ++r) {
        const int q = g*10 + r;
        float s = 0.f;
#pragma unroll 8
        for (int jj = 0; jj < 64; ++jj) s += qr[q][jj]*kv[j][jj];
        sv[r] = s * 0.125f;
      }
#pragma unroll
      for (int r = 0; r < 10; ++r) sl[g*10 + r][j] = sv[r];
    }
    __syncthreads();
    // issue V loads into regs (overlaps the row stats below)
    float4 vst[4];
    {
      const float* src = vbase + (size_t)(kb + srow)*512 + scb;
#pragma unroll
      for (int i = 0; i < 4; ++i) vst[i] = ld4(src + 4*i);
    }
    if (r4 < NU) {  // per-row running max + rescale factor (4 lanes per row)
      float tm = -INFINITY;
#pragma unroll
      for (int c = 0; c < 16; ++c) tm = fmaxf(tm, sl[r4][sub*16 + c]);
      tm = fmaxf(tm, __shfl_xor(tm, 1));
      tm = fmaxf(tm, __shfl_xor(tm, 2));
      const float nm = fmaxf(ms[r4], tm);
      if (sub == 0) { fs[r4] = expf(ms[r4] - nm); ms[r4] = nm; }
    }
    __syncthreads();
    {  // rescale acc, exponentiate scores in-place, stage V into kv
#pragma unroll
      for (int r = 0; r < 10; ++r) {
        const int q = g*10 + r;
        acc[r] *= fs[q];
        sl[q][j] = expf(sl[q][j] - ms[q]);
      }
#pragma unroll
      for (int i = 0; i < 4; ++i) {
        kv[srow][scb + 4*i + 0] = vst[i].x;
        kv[srow][scb + 4*i + 1] = vst[i].y;
        kv[srow][scb + 4*i + 2] = vst[i].z;
        kv[srow][scb + 4*i + 3] = vst[i].w;
      }
    }
    __syncthreads();
    if (r4 < NU) {  // l update (4 lanes per row)
      float s = 0.f;
#pragma unroll
      for (int c = 0; c < 16; ++c) s += sl[r4][sub*16 + c];
      s += __shfl_xor(s, 1);
      s += __shfl_xor(s, 2);
      if (sub == 0) ls[r4] = ls[r4]*fs[r4] + s;
    }
    {  // PV accumulate
#pragma unroll 4
      for (int kk = 0; kk < 64; ++kk) {
        const float vv = kv[kk][j];
#pragma unroll
        for (int r = 0; r < 10; ++r) acc[r] += sl[g*10 + r][kk]*vv;
      }
    }
  }
  __syncthreads();
  const size_t base = (size_t)(bh*16 + kt)*NU;
  if (t < NU) { pm[base + t] = ms[t]; pl[base + t] = ls[t]; }
#pragma unroll
  for (int r = 0; r < 10; ++r)
    pacc[(base + g*10 + r)*64 + j] = acc[r];
}

// ---------------------------------------------------------------- combine 16 partials, write outc (B,40,512)
__global__ __launch_bounds__(256) void flash_combine(const float* __restrict__ pm,
                                                     const float* __restrict__ pl,
                                                     const float* __restrict__ pacc,
                                                     float* __restrict__ outc) {
  const int t = threadIdx.x;
  const int qg = t >> 6, j = t & 63;
  const int bh = blockIdx.x / 10;
  const int q  = (blockIdx.x % 10)*4 + qg;
  const int b = bh >> 3, h = bh & 7;
  float m = -INFINITY;
#pragma unroll
  for (int kt = 0; kt < 16; ++kt) m = fmaxf(m, pm[(size_t)(bh*16 + kt)*NU + q]);
  float Lsum = 0.f, num = 0.f;
#pragma unroll
  for (int kt = 0; kt < 16; ++kt) {
    const size_t base = (size_t)(bh*16 + kt)*NU;
    const float w = expf(pm[base + q] - m);
    Lsum += w * pl[base + q];
    num  += w * pacc[(base + q)*64 + j];
  }
  outc[(size_t)(b*NU + q)*512 + h*64 + j] = num / Lsum;
}

// ---------------------------------------------------------------- Wo GEMM, split-k x4: pwo[ks] = outc @ Wo^T (K slab)
// grid (8 ntiles, 4 ksplit), 256 threads, 80x64 tile, 5x4 micro
__global__ __launch_bounds__(256) void wo_gemm(const float* __restrict__ outc,
                                               const float* __restrict__ Wo,
                                               float* __restrict__ pwo) {
  __shared__ __align__(16) float a_t[80][68];
  __shared__ __align__(16) float w_t[64][68];
  const int t = threadIdx.x;
  const int ty = t >> 4, tx = t & 15;
  const int nt = blockIdx.x, ks = blockIdx.y;
  float acc[5][4];
#pragma unroll
  for (int i = 0; i < 5; ++i)
#pragma unroll
    for (int j = 0; j < 4; ++j) acc[i][j] = 0.f;

  for (int c = 0; c < 2; ++c) {
    const int kb = ks*128 + c*64;
    __syncthreads();
#pragma unroll
    for (int i = 0; i < 20; ++i) {
      const int fi = t + 256*i;
      const int row = fi >> 6, col = fi & 63;
      a_t[row][col] = outc[(size_t)row*512 + kb + col];
    }
#pragma unroll
    for (int i = 0; i < 16; ++i) {
      const int fi = t + 256*i;
      const int row = fi >> 6, col = fi & 63;
      w_t[row][col] = Wo[(size_t)(nt*64 + row)*512 + kb + col];
    }
    __syncthreads();
    for (int gq = 0; gq < 16; ++gq) {
      float4 av[5], wv[4];
#pragma unroll
      for (int i = 0; i < 5; ++i) av[i] = *reinterpret_cast<const float4*>(&a_t[ty + 16*i][4*gq]);
#pragma unroll
      for (int j = 0; j < 4; ++j) wv[j] = *reinterpret_cast<const float4*>(&w_t[tx + 16*j][4*gq]);
#pragma unroll
      for (int i = 0; i < 5; ++i)
#pragma unroll
        for (int j = 0; j < 4; ++j) {
          acc[i][j] += av[i].x * wv[j].x;
          acc[i][j] += av[i].y * wv[j].y;
          acc[i][j] += av[i].z * wv[j].z;
          acc[i][j] += av[i].w * wv[j].w;
        }
    }
  }
#pragma unroll
  for (int i = 0; i < 5; ++i)
#pragma unroll
    for (int j = 0; j < 4; ++j)
      pwo[ks*40960 + (size_t)(ty + 16*i)*512 + nt*64 + tx + 16*j] = acc[i][j];
}

__global__ __launch_bounds__(256) void wo_combine(const float* __restrict__ pwo,
                                                  const float* __restrict__ bo,
                                                  float* __restrict__ out) {
  const int gi = blockIdx.x*256 + threadIdx.x;   // float4 index, 0..10239
  const float4* p = reinterpret_cast<const float4*>(pwo);
  const float4 a = p[gi], b4 = p[10240 + gi], c4 = p[20480 + gi], d4 = p[30720 + gi];
  const float4 bb = ld4(bo + 4*(gi & 127));
  float4 o;
  o.x = a.x + b4.x + c4.x + d4.x + bb.x;
  o.y = a.y + b4.y + c4.y + d4.y + bb.y;
  o.z = a.z + b4.z + c4.z + d4.z + bb.z;
  o.w = a.w + b4.w + c4.w + d4.w + bb.w;
  reinterpret_cast<float4*>(out)[gi] = o;
}

// ----------------------------------------------------------------
extern "C" void kernel_launch(void* const* d_in, const int* in_sizes, int n_in,
                              void* d_out, int out_size, void* d_ws, size_t ws_size,
                              hipStream_t stream) {
  const float* q  = (const float*)d_in[0];
  const float* k  = (const float*)d_in[1];
  const float* v  = (const float*)d_in[2];
  const float* Wq = (const float*)d_in[3];
  const float* bq = (const float*)d_in[4];
  const float* Wk = (const float*)d_in[5];
  const float* bk = (const float*)d_in[6];
  const float* Wv = (const float*)d_in[7];
  const float* bv = (const float*)d_in[8];
  const float* Wo = (const float*)d_in[9];
  const float* bo = (const float*)d_in[10];
  const int*  idx = (const int*)d_in[11];

  float* ws   = (float*)d_ws;
  float* qp   = ws;                        // 2,097,152
  float* kp   = ws + 2097152;              // 2,097,152
  float* vp   = ws + 4194304;              // 2,097,152
  float* ksum = ws + 6291456;              // 1,024
  int*   Mtop = (int*)(ws + 6292480);      // 640
  float* pm   = ws + 6293120;              // 10,240
  float* pl   = ws + 6303360;              // 10,240
  float* pacc = ws + 6313600;              // 655,360
  float* outc = ws + 6968960;              // 40,960  (end 7,009,920 floats = 28.04 MB)
  // time-disjoint aliases (sequential dispatches make these safe):
  float* Mp   = pm;                        // 65,536 needed <= pm+pl+pacc; dead before flash_partial
  float* pwo  = pm;                        // 163,840 needed; written after flash_combine reads pm/pl/pacc

  const dim3 blk(256);
  proj_gemm<<<dim3(32, 4, 3), blk, 0, stream>>>(q, k, v, Wq, Wk, Wv, bq, bk, bv, qp, kp, vp, 0);
  proj_gemm<<<dim3(32, 4, 3), blk, 0, stream>>>(q, k, v, Wq, Wk, Wv, bq, bk, bv, qp, kp, vp, 1);
  ksum_kernel<<<dim3(16), dim3(1024), 0, stream>>>(kp, idx, ksum);
  m_kernel<<<dim3(512), blk, 0, stream>>>(qp, kp, idx, Mp);
  topk_kernel<<<dim3(16), blk, 0, stream>>>(qp, ksum, Mp, Mtop);
  flash_partial<<<dim3(256), blk, 0, stream>>>(qp, kp, vp, Mtop, pm, pl, pacc);
  flash_combine<<<dim3(160), blk, 0, stream>>>(pm, pl, pacc, outc);
  wo_gemm<<<dim3(8, 4), blk, 0, stream>>>(outc, Wo, pwo);
  wo_combine<<<dim3(40), blk, 0, stream>>>(pwo, bo, (float*)d_out);
}

// Round 3
// 305.038 us; speedup vs baseline: 1.9550x; 1.2111x over previous
//
#include <hip/hip_runtime.h>
#include <math.h>

#define B_ 2
#define L_ 2048
#define D_ 512
#define H_ 8
#define DH 64
#define NS 2048   // U_part (sampled keys)
#define NU 40     // u (selected queries)
#define BHD (L_*D_)        // per-batch stride of qp/kp/vp
#define QHS (L_*DH)        // per-head stride inside qh view

typedef __attribute__((ext_vector_type(8))) short bf16x8;
typedef __attribute__((ext_vector_type(4))) float f32x4;

__device__ inline float4 ld4(const float* p) { return *reinterpret_cast<const float4*>(p); }

// bf16 round-to-nearest-even split helpers
__device__ inline unsigned short bf_rne(float x) {
  unsigned b = __float_as_uint(x);
  return (unsigned short)((b + 0x7FFFu + ((b >> 16) & 1u)) >> 16);
}
__device__ inline float bf_f(unsigned short h) { return __uint_as_float(((unsigned)h) << 16); }
__device__ inline void split3(float x, unsigned short& h, unsigned short& m, unsigned short& l) {
  h = bf_rne(x); float r = x - bf_f(h);
  m = bf_rne(r); r = r - bf_f(m);
  l = bf_rne(r);
}

// ---------------------------------------------------------------- fused projection GEMM
// C = A @ W^T ; kh=0: C = acc + bias (K 0..255), kh=1: C += acc (K 256..511)
__global__ __launch_bounds__(256) void proj_gemm(
    const float* __restrict__ qa, const float* __restrict__ ka, const float* __restrict__ va,
    const float* __restrict__ Wq, const float* __restrict__ Wk, const float* __restrict__ Wv,
    const float* __restrict__ bq, const float* __restrict__ bk, const float* __restrict__ bv,
    float* __restrict__ qp, float* __restrict__ kp, float* __restrict__ vp, int kh)
{
  __shared__ __align__(16) float a_t[128][36];
  __shared__ __align__(16) float w_t[128][36];
  const int t = threadIdx.x;
  const int ty = t >> 4, tx = t & 15;
  const int mat = blockIdx.z;
  const float* A    = (mat == 0) ? qa : (mat == 1) ? ka : va;
  const float* W    = (mat == 0) ? Wq : (mat == 1) ? Wk : Wv;
  const float* bias = (mat == 0) ? bq : (mat == 1) ? bk : bv;
  float* C          = (mat == 0) ? qp : (mat == 1) ? kp : vp;
  const int m0 = blockIdx.x * 128, n0 = blockIdx.y * 128;
  const int srow = t >> 3, scol = (t & 7) * 4;

  float acc[8][8];
#pragma unroll
  for (int i = 0; i < 8; ++i)
#pragma unroll
    for (int j = 0; j < 8; ++j) acc[i][j] = 0.f;

  for (int c = 0; c < 8; ++c) {
    const int kb = kh * 256 + c * 32;
    __syncthreads();
#pragma unroll
    for (int i = 0; i < 4; ++i) {
      const int row = srow + 32 * i;
      *reinterpret_cast<float4*>(&a_t[row][scol]) = ld4(A + (size_t)(m0 + row) * 512 + kb + scol);
      *reinterpret_cast<float4*>(&w_t[row][scol]) = ld4(W + (size_t)(n0 + row) * 512 + kb + scol);
    }
    __syncthreads();
    for (int g = 0; g < 8; ++g) {
      float4 av[8], wv[8];
#pragma unroll
      for (int i = 0; i < 8; ++i) av[i] = *reinterpret_cast<const float4*>(&a_t[ty + 16 * i][4 * g]);
#pragma unroll
      for (int j = 0; j < 8; ++j) wv[j] = *reinterpret_cast<const float4*>(&w_t[tx + 16 * j][4 * g]);
#pragma unroll
      for (int i = 0; i < 8; ++i)
#pragma unroll
        for (int j = 0; j < 8; ++j) {
          acc[i][j] += av[i].x * wv[j].x;
          acc[i][j] += av[i].y * wv[j].y;
          acc[i][j] += av[i].z * wv[j].z;
          acc[i][j] += av[i].w * wv[j].w;
        }
    }
  }
#pragma unroll
  for (int i = 0; i < 8; ++i) {
    const int gm = m0 + ty + 16 * i;
#pragma unroll
    for (int j = 0; j < 8; ++j) {
      const int gn = n0 + tx + 16 * j;
      if (kh == 0) C[(size_t)gm * 512 + gn] = acc[i][j] + bias[gn];
      else         C[(size_t)gm * 512 + gn] += acc[i][j];
    }
  }
}

// ---------------------------------------------------------------- Ksum[bh][j] = sum_s kp[b, idx[s], h*64+j]
__global__ __launch_bounds__(1024) void ksum_kernel(const float* __restrict__ kp,
                                                    const int* __restrict__ idx,
                                                    float* __restrict__ ksum) {
  __shared__ float part[16][64];
  const int bh = blockIdx.x;
  const int b = bh >> 3, h = bh & 7;
  const int t = threadIdx.x;
  const int sg = t >> 6, j = t & 63;
  const float* kbase = kp + (size_t)b*BHD + h*DH;
  float a = 0.f;
  for (int s = sg*128; s < sg*128 + 128; ++s)
    a += kbase[(size_t)idx[s]*512 + j];
  part[sg][j] = a;
  __syncthreads();
  if (t < 64) {
    float s = 0.f;
#pragma unroll
    for (int i = 0; i < 16; ++i) s += part[i][t];
    ksum[bh*64 + t] = s;
  }
}

// ---------------------------------------------------------------- Mp[ks][bh][q] = max over 1024 sampled keys of q.k
// split-bf16 MFMA (6 products ~ fp32 accuracy). grid 512: bh=bid>>5, qt=(bid>>1)&15 (128-q tiles), ks=bid&1.
// 4 waves; wave w owns q rows qt*128 + w*32 .. +32. K-tile = 128 sampled keys staged as 3 bf16 planes in LDS.
__global__ __launch_bounds__(256, 2) void m_kernel(const float* __restrict__ qp,
                                                   const float* __restrict__ kp,
                                                   const int* __restrict__ idx,
                                                   float* __restrict__ Mp) {
  __shared__ __align__(16) unsigned short k3[3][128][72];   // 144B row stride: b128-aligned, ~2-way banks
  const int t = threadIdx.x;
  const int bid = blockIdx.x;
  const int bh = bid >> 5, qt = (bid >> 1) & 15, ks = bid & 1;
  const int b = bh >> 3, h = bh & 7;
  const int w = t >> 6, l = t & 63;
  const int lr = l & 15;       // fragment row lane
  const int lg = l >> 4;       // k-group (d-chunk of 8)

  // ---- A fragments: q rows (qt*128 + w*32 + m*16 + lr), d = c*32 + lg*8 + e, split 3-way once
  bf16x8 qf[2][2][3];          // [m][kstep][split]
  {
    const float* qbase = qp + (size_t)b*BHD + (size_t)h*QHS + (size_t)(qt*128 + w*32 + lr) * 64 + lg*8;
#pragma unroll
    for (int m = 0; m < 2; ++m)
#pragma unroll
      for (int c = 0; c < 2; ++c) {
        const float* src = qbase + m*16*64 + c*32;
        float4 x0 = ld4(src), x1 = ld4(src + 4);
        float xs[8] = {x0.x, x0.y, x0.z, x0.w, x1.x, x1.y, x1.z, x1.w};
        union { bf16x8 v; unsigned short u[8]; } H, M, L;
#pragma unroll
        for (int e = 0; e < 8; ++e) split3(xs[e], H.u[e], M.u[e], L.u[e]);
        qf[m][c][0] = H.v; qf[m][c][1] = M.v; qf[m][c][2] = L.v;
      }
  }

  const float* kbase = kp + (size_t)b*BHD + h*DH;
  const int ib = ks * 1024;
  const int srow = t >> 1, sh = (t & 1) * 32;   // thread stages row srow, d-cols [sh, sh+32)

  // prefetch tile 0 into regs
  float4 vst[8];
  {
    const int kr = idx[ib + srow];
    const float* src = kbase + (size_t)kr * 512 + sh;
#pragma unroll
    for (int i = 0; i < 8; ++i) vst[i] = ld4(src + 4*i);
  }

  float mx[2][4];
#pragma unroll
  for (int m = 0; m < 2; ++m)
#pragma unroll
    for (int r = 0; r < 4; ++r) mx[m][r] = -INFINITY;

  for (int tl = 0; tl < 8; ++tl) {
    __syncthreads();                       // prev tile's MFMA reads of k3 complete
    {  // convert staged regs -> 3 bf16 planes (b128 stores)
#pragma unroll
      for (int e2 = 0; e2 < 4; ++e2) {
        union { bf16x8 v; unsigned short u[8]; } H, M, L;
        float xs[8] = {vst[2*e2].x, vst[2*e2].y, vst[2*e2].z, vst[2*e2].w,
                       vst[2*e2+1].x, vst[2*e2+1].y, vst[2*e2+1].z, vst[2*e2+1].w};
#pragma unroll
        for (int e = 0; e < 8; ++e) split3(xs[e], H.u[e], M.u[e], L.u[e]);
        *reinterpret_cast<bf16x8*>(&k3[0][srow][sh + 8*e2]) = H.v;
        *reinterpret_cast<bf16x8*>(&k3[1][srow][sh + 8*e2]) = M.v;
        *reinterpret_cast<bf16x8*>(&k3[2][srow][sh + 8*e2]) = L.v;
      }
    }
    if (tl < 7) {  // prefetch next tile (latency hides under MFMA loop)
      const int kr = idx[ib + (tl+1)*128 + srow];
      const float* src = kbase + (size_t)kr * 512 + sh;
#pragma unroll
      for (int i = 0; i < 8; ++i) vst[i] = ld4(src + 4*i);
    }
    __syncthreads();                       // k3 ready

    for (int n2 = 0; n2 < 4; ++n2) {       // 2 key-column groups of 16 per step -> 4 indep acc chains
      bf16x8 bf[2][3][2];                  // [nsub][split][kstep]
#pragma unroll
      for (int ns = 0; ns < 2; ++ns)
#pragma unroll
        for (int s = 0; s < 3; ++s)
#pragma unroll
          for (int c = 0; c < 2; ++c)
            bf[ns][s][c] = *reinterpret_cast<const bf16x8*>(&k3[s][n2*32 + ns*16 + lr][c*32 + lg*8]);
#pragma unroll
      for (int m = 0; m < 2; ++m)
#pragma unroll
        for (int ns = 0; ns < 2; ++ns) {
          f32x4 acc = {0.f, 0.f, 0.f, 0.f};
#pragma unroll
          for (int c = 0; c < 2; ++c) acc = __builtin_amdgcn_mfma_f32_16x16x32_bf16(qf[m][c][0], bf[ns][0][c], acc, 0, 0, 0); // hh
#pragma unroll
          for (int c = 0; c < 2; ++c) acc = __builtin_amdgcn_mfma_f32_16x16x32_bf16(qf[m][c][0], bf[ns][1][c], acc, 0, 0, 0); // hm
#pragma unroll
          for (int c = 0; c < 2; ++c) acc = __builtin_amdgcn_mfma_f32_16x16x32_bf16(qf[m][c][1], bf[ns][0][c], acc, 0, 0, 0); // mh
#pragma unroll
          for (int c = 0; c < 2; ++c) acc = __builtin_amdgcn_mfma_f32_16x16x32_bf16(qf[m][c][1], bf[ns][1][c], acc, 0, 0, 0); // mm
#pragma unroll
          for (int c = 0; c < 2; ++c) acc = __builtin_amdgcn_mfma_f32_16x16x32_bf16(qf[m][c][0], bf[ns][2][c], acc, 0, 0, 0); // hl
#pragma unroll
          for (int c = 0; c < 2; ++c) acc = __builtin_amdgcn_mfma_f32_16x16x32_bf16(qf[m][c][2], bf[ns][0][c], acc, 0, 0, 0); // lh
#pragma unroll
          for (int r = 0; r < 4; ++r) mx[m][r] = fmaxf(mx[m][r], acc[r]);
        }
    }
  }

  // reduce max across the 16 key-lanes; C layout: row=(l>>4)*4+reg, col=l&15
#pragma unroll
  for (int m = 0; m < 2; ++m)
#pragma unroll
    for (int r = 0; r < 4; ++r) {
      float v = mx[m][r];
      v = fmaxf(v, __shfl_xor(v, 1));
      v = fmaxf(v, __shfl_xor(v, 2));
      v = fmaxf(v, __shfl_xor(v, 4));
      v = fmaxf(v, __shfl_xor(v, 8));
      if (lr == 0)
        Mp[ks*32768 + bh*2048 + qt*128 + w*32 + m*16 + lg*4 + r] = v;
    }
}

// ---------------------------------------------------------------- fused M-finalize + top-40 (stable, == top_k(-M))
__global__ __launch_bounds__(256) void topk_kernel(const float* __restrict__ qp,
                                                   const float* __restrict__ ksum,
                                                   const float* __restrict__ Mp,
                                                   int* __restrict__ Mtop) {
  __shared__ float mv[2048];
  __shared__ float ks_s[64];
  __shared__ float wvs[4];
  __shared__ int   wis[4];
  const int bh = blockIdx.x;
  const int b = bh >> 3, h = bh & 7;
  const int t = threadIdx.x;
  if (t < 64) ks_s[t] = ksum[bh*64 + t];
  __syncthreads();
#pragma unroll
  for (int c = 0; c < 8; ++c) {
    const int qi = c * 256 + t;
    const float* qrow = qp + (size_t)b*BHD + (size_t)h*QHS + (size_t)qi * 64;
    float dot = 0.f;
#pragma unroll
    for (int cc = 0; cc < 16; ++cc) {
      float4 q4 = ld4(qrow + 4 * cc);
      dot += q4.x * ks_s[4*cc + 0];
      dot += q4.y * ks_s[4*cc + 1];
      dot += q4.z * ks_s[4*cc + 2];
      dot += q4.w * ks_s[4*cc + 3];
    }
    mv[qi] = fmaxf(Mp[bh*2048 + qi], Mp[32768 + bh*2048 + qi]) - dot * (1.0f/2048.0f);
  }
  __syncthreads();
  const int wl = t & 63, w = t >> 6;
  for (int it = 0; it < NU; ++it) {
    float bv = mv[t]; int bi = t;
#pragma unroll
    for (int c = 1; c < 8; ++c) {
      const float v = mv[t + 256*c];
      if (v < bv) { bv = v; bi = t + 256*c; }
    }
#pragma unroll
    for (int off = 1; off < 64; off <<= 1) {
      const float ov = __shfl_xor(bv, off);
      const int   oi = __shfl_xor(bi, off);
      if (ov < bv || (ov == bv && oi < bi)) { bv = ov; bi = oi; }
    }
    if (wl == 0) { wvs[w] = bv; wis[w] = bi; }
    __syncthreads();
    if (t == 0) {
      float fv = wvs[0]; int fi = wis[0];
#pragma unroll
      for (int w2 = 1; w2 < 4; ++w2)
        if (wvs[w2] < fv || (wvs[w2] == fv && wis[w2] < fi)) { fv = wvs[w2]; fi = wis[w2]; }
      Mtop[bh*NU + it] = fi;
      mv[fi] = INFINITY;
    }
    __syncthreads();
  }
}

// ---------------------------------------------------------------- flash partials over 128-key slabs
__global__ __launch_bounds__(256) void flash_partial(const float* __restrict__ qp,
                                                     const float* __restrict__ kp,
                                                     const float* __restrict__ vp,
                                                     const int* __restrict__ Mtop,
                                                     float* __restrict__ pm,
                                                     float* __restrict__ pl,
                                                     float* __restrict__ pacc) {
  __shared__ float qr[NU][65];
  __shared__ float kv[64][65];
  __shared__ float sl[NU][65];
  __shared__ float ms[NU], ls[NU], fs[NU];
  const int bid = blockIdx.x;
  const int bh = bid >> 4, kt = bid & 15;
  const int b = bh >> 3, h = bh & 7;
  const int t = threadIdx.x;
  const int g = t >> 6, j = t & 63;
  const int r4 = t >> 2, sub = t & 3;

  {
    const float* qbase = qp + (size_t)b*BHD + (size_t)h*QHS;
#pragma unroll
    for (int r = 0; r < 10; ++r) {
      const int q = g*10 + r;
      qr[q][j] = qbase[(size_t)Mtop[bh*NU + q]*64 + j];
    }
  }
  if (t < NU) { ms[t] = -INFINITY; ls[t] = 0.f; }
  float acc[10];
#pragma unroll
  for (int r = 0; r < 10; ++r) acc[r] = 0.f;

  const float* kbase = kp + (size_t)b*BHD + h*DH;
  const float* vbase = vp + (size_t)b*BHD + h*DH;
  const int srow = t >> 2, scb = (t & 3)*16;

  for (int st = 0; st < 2; ++st) {
    const int kb = kt*128 + st*64;
    __syncthreads();
    {
      const float* src = kbase + (size_t)(kb + srow)*512 + scb;
#pragma unroll
      for (int i = 0; i < 4; ++i) {
        float4 v = ld4(src + 4*i);
        kv[srow][scb + 4*i + 0] = v.x;
        kv[srow][scb + 4*i + 1] = v.y;
        kv[srow][scb + 4*i + 2] = v.z;
        kv[srow][scb + 4*i + 3] = v.w;
      }
    }
    __syncthreads();
    {
      float sv[10];
#pragma unroll
      for (int r = 0; r < 10; ++r) {
        const int q = g*10 + r;
        float s = 0.f;
#pragma unroll 8
        for (int jj = 0; jj < 64; ++jj) s += qr[q][jj]*kv[j][jj];
        sv[r] = s * 0.125f;
      }
#pragma unroll
      for (int r = 0; r < 10; ++r) sl[g*10 + r][j] = sv[r];
    }
    __syncthreads();
    float4 vst[4];
    {
      const float* src = vbase + (size_t)(kb + srow)*512 + scb;
#pragma unroll
      for (int i = 0; i < 4; ++i) vst[i] = ld4(src + 4*i);
    }
    if (r4 < NU) {
      float tm = -INFINITY;
#pragma unroll
      for (int c = 0; c < 16; ++c) tm = fmaxf(tm, sl[r4][sub*16 + c]);
      tm = fmaxf(tm, __shfl_xor(tm, 1));
      tm = fmaxf(tm, __shfl_xor(tm, 2));
      const float nm = fmaxf(ms[r4], tm);
      if (sub == 0) { fs[r4] = expf(ms[r4] - nm); ms[r4] = nm; }
    }
    __syncthreads();
    {
#pragma unroll
      for (int r = 0; r < 10; ++r) {
        const int q = g*10 + r;
        acc[r] *= fs[q];
        sl[q][j] = expf(sl[q][j] - ms[q]);
      }
#pragma unroll
      for (int i = 0; i < 4; ++i) {
        kv[srow][scb + 4*i + 0] = vst[i].x;
        kv[srow][scb + 4*i + 1] = vst[i].y;
        kv[srow][scb + 4*i + 2] = vst[i].z;
        kv[srow][scb + 4*i + 3] = vst[i].w;
      }
    }
    __syncthreads();
    if (r4 < NU) {
      float s = 0.f;
#pragma unroll
      for (int c = 0; c < 16; ++c) s += sl[r4][sub*16 + c];
      s += __shfl_xor(s, 1);
      s += __shfl_xor(s, 2);
      if (sub == 0) ls[r4] = ls[r4]*fs[r4] + s;
    }
    {
#pragma unroll 4
      for (int kk = 0; kk < 64; ++kk) {
        const float vv = kv[kk][j];
#pragma unroll
        for (int r = 0; r < 10; ++r) acc[r] += sl[g*10 + r][kk]*vv;
      }
    }
  }
  __syncthreads();
  const size_t base = (size_t)(bh*16 + kt)*NU;
  if (t < NU) { pm[base + t] = ms[t]; pl[base + t] = ls[t]; }
#pragma unroll
  for (int r = 0; r < 10; ++r)
    pacc[(base + g*10 + r)*64 + j] = acc[r];
}

// ---------------------------------------------------------------- combine 16 partials, write outc (B,40,512)
__global__ __launch_bounds__(256) void flash_combine(const float* __restrict__ pm,
                                                     const float* __restrict__ pl,
                                                     const float* __restrict__ pacc,
                                                     float* __restrict__ outc) {
  const int t = threadIdx.x;
  const int qg = t >> 6, j = t & 63;
  const int bh = blockIdx.x / 10;
  const int q  = (blockIdx.x % 10)*4 + qg;
  const int b = bh >> 3, h = bh & 7;
  float m = -INFINITY;
#pragma unroll
  for (int kt = 0; kt < 16; ++kt) m = fmaxf(m, pm[(size_t)(bh*16 + kt)*NU + q]);
  float Lsum = 0.f, num = 0.f;
#pragma unroll
  for (int kt = 0; kt < 16; ++kt) {
    const size_t base = (size_t)(bh*16 + kt)*NU;
    const float w = expf(pm[base + q] - m);
    Lsum += w * pl[base + q];
    num  += w * pacc[(base + q)*64 + j];
  }
  outc[(size_t)(b*NU + q)*512 + h*64 + j] = num / Lsum;
}

// ---------------------------------------------------------------- Wo GEMM, split-k x4
__global__ __launch_bounds__(256) void wo_gemm(const float* __restrict__ outc,
                                               const float* __restrict__ Wo,
                                               float* __restrict__ pwo) {
  __shared__ __align__(16) float a_t[80][68];
  __shared__ __align__(16) float w_t[64][68];
  const int t = threadIdx.x;
  const int ty = t >> 4, tx = t & 15;
  const int nt = blockIdx.x, ks = blockIdx.y;
  float acc[5][4];
#pragma unroll
  for (int i = 0; i < 5; ++i)
#pragma unroll
    for (int j = 0; j < 4; ++j) acc[i][j] = 0.f;

  for (int c = 0; c < 2; ++c) {
    const int kb = ks*128 + c*64;
    __syncthreads();
#pragma unroll
    for (int i = 0; i < 20; ++i) {
      const int fi = t + 256*i;
      const int row = fi >> 6, col = fi & 63;
      a_t[row][col] = outc[(size_t)row*512 + kb + col];
    }
#pragma unroll
    for (int i = 0; i < 16; ++i) {
      const int fi = t + 256*i;
      const int row = fi >> 6, col = fi & 63;
      w_t[row][col] = Wo[(size_t)(nt*64 + row)*512 + kb + col];
    }
    __syncthreads();
    for (int gq = 0; gq < 16; ++gq) {
      float4 av[5], wv[4];
#pragma unroll
      for (int i = 0; i < 5; ++i) av[i] = *reinterpret_cast<const float4*>(&a_t[ty + 16*i][4*gq]);
#pragma unroll
      for (int j = 0; j < 4; ++j) wv[j] = *reinterpret_cast<const float4*>(&w_t[tx + 16*j][4*gq]);
#pragma unroll
      for (int i = 0; i < 5; ++i)
#pragma unroll
        for (int j = 0; j < 4; ++j) {
          acc[i][j] += av[i].x * wv[j].x;
          acc[i][j] += av[i].y * wv[j].y;
          acc[i][j] += av[i].z * wv[j].z;
          acc[i][j] += av[i].w * wv[j].w;
        }
    }
  }
#pragma unroll
  for (int i = 0; i < 5; ++i)
#pragma unroll
    for (int j = 0; j < 4; ++j)
      pwo[ks*40960 + (size_t)(ty + 16*i)*512 + nt*64 + tx + 16*j] = acc[i][j];
}

__global__ __launch_bounds__(256) void wo_combine(const float* __restrict__ pwo,
                                                  const float* __restrict__ bo,
                                                  float* __restrict__ out) {
  const int gi = blockIdx.x*256 + threadIdx.x;
  const float4* p = reinterpret_cast<const float4*>(pwo);
  const float4 a = p[gi], b4 = p[10240 + gi], c4 = p[20480 + gi], d4 = p[30720 + gi];
  const float4 bb = ld4(bo + 4*(gi & 127));
  float4 o;
  o.x = a.x + b4.x + c4.x + d4.x + bb.x;
  o.y = a.y + b4.y + c4.y + d4.y + bb.y;
  o.z = a.z + b4.z + c4.z + d4.z + bb.z;
  o.w = a.w + b4.w + c4.w + d4.w + bb.w;
  reinterpret_cast<float4*>(out)[gi] = o;
}

// ----------------------------------------------------------------
extern "C" void kernel_launch(void* const* d_in, const int* in_sizes, int n_in,
                              void* d_out, int out_size, void* d_ws, size_t ws_size,
                              hipStream_t stream) {
  const float* q  = (const float*)d_in[0];
  const float* k  = (const float*)d_in[1];
  const float* v  = (const float*)d_in[2];
  const float* Wq = (const float*)d_in[3];
  const float* bq = (const float*)d_in[4];
  const float* Wk = (const float*)d_in[5];
  const float* bk = (const float*)d_in[6];
  const float* Wv = (const float*)d_in[7];
  const float* bv = (const float*)d_in[8];
  const float* Wo = (const float*)d_in[9];
  const float* bo = (const float*)d_in[10];
  const int*  idx = (const int*)d_in[11];

  float* ws   = (float*)d_ws;
  float* qp   = ws;                        // 2,097,152
  float* kp   = ws + 2097152;              // 2,097,152
  float* vp   = ws + 4194304;              // 2,097,152
  float* ksum = ws + 6291456;              // 1,024
  int*   Mtop = (int*)(ws + 6292480);      // 640
  float* pm   = ws + 6293120;              // 10,240
  float* pl   = ws + 6303360;              // 10,240
  float* pacc = ws + 6313600;              // 655,360
  float* outc = ws + 6968960;              // 40,960
  // time-disjoint aliases:
  float* Mp   = pm;                        // 65,536 needed; dead before flash_partial
  float* pwo  = pm;                        // 163,840 needed; written after flash_combine reads pm/pl/pacc

  const dim3 blk(256);
  proj_gemm<<<dim3(32, 4, 3), blk, 0, stream>>>(q, k, v, Wq, Wk, Wv, bq, bk, bv, qp, kp, vp, 0);
  proj_gemm<<<dim3(32, 4, 3), blk, 0, stream>>>(q, k, v, Wq, Wk, Wv, bq, bk, bv, qp, kp, vp, 1);
  ksum_kernel<<<dim3(16), dim3(1024), 0, stream>>>(kp, idx, ksum);
  m_kernel<<<dim3(512), blk, 0, stream>>>(qp, kp, idx, Mp);
  topk_kernel<<<dim3(16), blk, 0, stream>>>(qp, ksum, Mp, Mtop);
  flash_partial<<<dim3(256), blk, 0, stream>>>(qp, kp, vp, Mtop, pm, pl, pacc);
  flash_combine<<<dim3(160), blk, 0, stream>>>(pm, pl, pacc, outc);
  wo_gemm<<<dim3(8, 4), blk, 0, stream>>>(outc, Wo, pwo);
  wo_combine<<<dim3(40), blk, 0, stream>>>(pwo, bo, (float*)d_out);
}

// Round 4
// 226.531 us; speedup vs baseline: 2.6325x; 1.3466x over previous
//
#include <hip/hip_runtime.h>
#include <math.h>

#define B_ 2
#define L_ 2048
#define D_ 512
#define H_ 8
#define DH 64
#define NS 2048   // U_part (sampled keys)
#define NU 40     // u (selected queries)
#define BHD (L_*D_)        // per-batch stride of qp/kp/vp
#define QHS (L_*DH)        // per-head stride inside qh view

typedef __attribute__((ext_vector_type(8))) short bf16x8;
typedef __attribute__((ext_vector_type(4))) float f32x4;

__device__ inline float4 ld4(const float* p) { return *reinterpret_cast<const float4*>(p); }

// truncation split: x = h + m + r, all bf16-representable (exact truncations),
// |m| <= 2^-8|x|, |r_bf| captures to 2^-24|x|. 6-product MFMA == fp32-class dot.
__device__ inline unsigned short hi16(float x) { return (unsigned short)(__float_as_uint(x) >> 16); }
__device__ inline float trunchf(float x) { return __uint_as_float(__float_as_uint(x) & 0xFFFF0000u); }
__device__ inline void tsplit(float x, unsigned short& hs, unsigned short& ms, unsigned short& ls) {
  float h = trunchf(x); hs = hi16(x);
  float r = x - h;                 // exact
  float m = trunchf(r); ms = hi16(r);
  float r2 = r - m;                // exact
  ls = hi16(r2);
}

// ---------------------------------------------------------------- projection GEMM, split-bf16 MFMA
// C = A @ W^T + bias. A: 4096x512, W: 512x512. grid (32 mtiles, 4 ntiles, 3 mats).
// 256 thr = 4 waves (2x2), wave tile 64x64 (m=4, n=4), Kblk=32, 16 chunks.
__global__ __launch_bounds__(256) void proj_mfma(
    const float* __restrict__ qa, const float* __restrict__ ka, const float* __restrict__ va,
    const float* __restrict__ Wq, const float* __restrict__ Wk, const float* __restrict__ Wv,
    const float* __restrict__ bq, const float* __restrict__ bk, const float* __restrict__ bv,
    float* __restrict__ qp, float* __restrict__ kp, float* __restrict__ vp)
{
  __shared__ __align__(16) unsigned short a3[3][128][36];   // 72B rows: b128-aligned, ~2-way banks
  __shared__ __align__(16) unsigned short w3[3][128][36];
  const int t = threadIdx.x;
  const int mat = blockIdx.z;
  const float* A    = (mat == 0) ? qa : (mat == 1) ? ka : va;
  const float* W    = (mat == 0) ? Wq : (mat == 1) ? Wk : Wv;
  const float* bias = (mat == 0) ? bq : (mat == 1) ? bk : bv;
  float* C          = (mat == 0) ? qp : (mat == 1) ? kp : vp;
  const int m0 = blockIdx.x * 128, n0 = blockIdx.y * 128;
  const int w = t >> 6, l = t & 63;
  const int wm = w >> 1, wn = w & 1;
  const int lr = l & 15, lg = l >> 4;
  const int srow = t >> 1, sc0 = (t & 1) * 16;

  f32x4 acc[4][4];
#pragma unroll
  for (int i = 0; i < 4; ++i)
#pragma unroll
    for (int j = 0; j < 4; ++j) acc[i][j] = (f32x4){0.f, 0.f, 0.f, 0.f};

  for (int kc = 0; kc < 16; ++kc) {
    const int kb = kc * 32;
    __syncthreads();                       // prior MFMA reads done
    {  // stage A tile rows m0+srow, 16 k-cols, trunc-split -> 3 planes
      const float* src = A + (size_t)(m0 + srow) * 512 + kb + sc0;
      float xs[16];
#pragma unroll
      for (int i = 0; i < 4; ++i) {
        float4 v4 = ld4(src + 4*i);
        xs[4*i] = v4.x; xs[4*i+1] = v4.y; xs[4*i+2] = v4.z; xs[4*i+3] = v4.w;
      }
#pragma unroll
      for (int hh = 0; hh < 2; ++hh) {
        union { bf16x8 v; unsigned short u[8]; } H, M, L;
#pragma unroll
        for (int e = 0; e < 8; ++e) tsplit(xs[hh*8 + e], H.u[e], M.u[e], L.u[e]);
        *reinterpret_cast<bf16x8*>(&a3[0][srow][sc0 + 8*hh]) = H.v;
        *reinterpret_cast<bf16x8*>(&a3[1][srow][sc0 + 8*hh]) = M.v;
        *reinterpret_cast<bf16x8*>(&a3[2][srow][sc0 + 8*hh]) = L.v;
      }
    }
    {  // stage W tile rows n0+srow
      const float* src = W + (size_t)(n0 + srow) * 512 + kb + sc0;
      float xs[16];
#pragma unroll
      for (int i = 0; i < 4; ++i) {
        float4 v4 = ld4(src + 4*i);
        xs[4*i] = v4.x; xs[4*i+1] = v4.y; xs[4*i+2] = v4.z; xs[4*i+3] = v4.w;
      }
#pragma unroll
      for (int hh = 0; hh < 2; ++hh) {
        union { bf16x8 v; unsigned short u[8]; } H, M, L;
#pragma unroll
        for (int e = 0; e < 8; ++e) tsplit(xs[hh*8 + e], H.u[e], M.u[e], L.u[e]);
        *reinterpret_cast<bf16x8*>(&w3[0][srow][sc0 + 8*hh]) = H.v;
        *reinterpret_cast<bf16x8*>(&w3[1][srow][sc0 + 8*hh]) = M.v;
        *reinterpret_cast<bf16x8*>(&w3[2][srow][sc0 + 8*hh]) = L.v;
      }
    }
    __syncthreads();                       // planes ready

    bf16x8 af[3][4], bf[3][4];
#pragma unroll
    for (int p = 0; p < 3; ++p)
#pragma unroll
      for (int mi = 0; mi < 4; ++mi)
        af[p][mi] = *reinterpret_cast<const bf16x8*>(&a3[p][wm*64 + mi*16 + lr][lg*8]);
#pragma unroll
    for (int p = 0; p < 3; ++p)
#pragma unroll
      for (int ni = 0; ni < 4; ++ni)
        bf[p][ni] = *reinterpret_cast<const bf16x8*>(&w3[p][wn*64 + ni*16 + lr][lg*8]);
#pragma unroll
    for (int mi = 0; mi < 4; ++mi)
#pragma unroll
      for (int ni = 0; ni < 4; ++ni) {
        acc[mi][ni] = __builtin_amdgcn_mfma_f32_16x16x32_bf16(af[0][mi], bf[0][ni], acc[mi][ni], 0, 0, 0); // hh
        acc[mi][ni] = __builtin_amdgcn_mfma_f32_16x16x32_bf16(af[0][mi], bf[1][ni], acc[mi][ni], 0, 0, 0); // hm
        acc[mi][ni] = __builtin_amdgcn_mfma_f32_16x16x32_bf16(af[1][mi], bf[0][ni], acc[mi][ni], 0, 0, 0); // mh
        acc[mi][ni] = __builtin_amdgcn_mfma_f32_16x16x32_bf16(af[1][mi], bf[1][ni], acc[mi][ni], 0, 0, 0); // mm
        acc[mi][ni] = __builtin_amdgcn_mfma_f32_16x16x32_bf16(af[0][mi], bf[2][ni], acc[mi][ni], 0, 0, 0); // hl
        acc[mi][ni] = __builtin_amdgcn_mfma_f32_16x16x32_bf16(af[2][mi], bf[0][ni], acc[mi][ni], 0, 0, 0); // lh
      }
  }
  // epilogue: D row = M (lg*4+r), col = N (lr)
#pragma unroll
  for (int mi = 0; mi < 4; ++mi)
#pragma unroll
    for (int ni = 0; ni < 4; ++ni) {
      const int gn = n0 + wn*64 + ni*16 + lr;
      const float bv_ = bias[gn];
#pragma unroll
      for (int r = 0; r < 4; ++r) {
        const int gm = m0 + wm*64 + mi*16 + lg*4 + r;
        C[(size_t)gm * 512 + gn] = acc[mi][ni][r] + bv_;
      }
    }
}

// ---------------------------------------------------------------- Ksum[bh][j] = sum_s kp[b, idx[s], h*64+j]
__global__ __launch_bounds__(1024) void ksum_kernel(const float* __restrict__ kp,
                                                    const int* __restrict__ idx,
                                                    float* __restrict__ ksum) {
  __shared__ float part[16][64];
  const int bh = blockIdx.x;
  const int b = bh >> 3, h = bh & 7;
  const int t = threadIdx.x;
  const int sg = t >> 6, j = t & 63;
  const float* kbase = kp + (size_t)b*BHD + h*DH;
  float a = 0.f;
  for (int s = sg*128; s < sg*128 + 128; ++s)
    a += kbase[(size_t)idx[s]*512 + j];
  part[sg][j] = a;
  __syncthreads();
  if (t < 64) {
    float s = 0.f;
#pragma unroll
    for (int i = 0; i < 16; ++i) s += part[i][t];
    ksum[bh*64 + t] = s;
  }
}

// ---------------------------------------------------------------- Mp[ks][bh][q] = max over 1024 sampled keys of q.k
// split-bf16 MFMA, wave m=4 (64 q-rows). grid 256: bh=bid>>4, qt=(bid>>1)&7 (256-q tiles), ks=bid&1.
__global__ __launch_bounds__(256) void m_kernel(const float* __restrict__ qp,
                                                const float* __restrict__ kp,
                                                const int* __restrict__ idx,
                                                float* __restrict__ Mp) {
  __shared__ __align__(16) unsigned short k3[3][128][72];   // 144B rows
  const int t = threadIdx.x;
  const int bid = blockIdx.x;
  const int bh = bid >> 4, qt = (bid >> 1) & 7, ks = bid & 1;
  const int b = bh >> 3, h = bh & 7;
  const int w = t >> 6, l = t & 63;
  const int lr = l & 15;       // fragment row lane
  const int lg = l >> 4;       // k-group (d-chunk of 8)

  // A fragments: q rows (qt*256 + w*64 + mi*16 + lr), d = c*32 + lg*8, trunc-split once
  bf16x8 qf[4][2][3];          // [mi][kstep][plane]
  {
    const float* qbase = qp + (size_t)b*BHD + (size_t)h*QHS + (size_t)(qt*256 + w*64 + lr) * 64 + lg*8;
#pragma unroll
    for (int mi = 0; mi < 4; ++mi)
#pragma unroll
      for (int c = 0; c < 2; ++c) {
        const float* src = qbase + mi*16*64 + c*32;
        float4 x0 = ld4(src), x1 = ld4(src + 4);
        float xs[8] = {x0.x, x0.y, x0.z, x0.w, x1.x, x1.y, x1.z, x1.w};
        union { bf16x8 v; unsigned short u[8]; } H, M, L;
#pragma unroll
        for (int e = 0; e < 8; ++e) tsplit(xs[e], H.u[e], M.u[e], L.u[e]);
        qf[mi][c][0] = H.v; qf[mi][c][1] = M.v; qf[mi][c][2] = L.v;
      }
  }

  const float* kbase = kp + (size_t)b*BHD + h*DH;
  const int ib = ks * 1024;
  const int srow = t >> 1, sh = (t & 1) * 32;

  // prefetch tile 0
  float4 vst[8];
  {
    const int kr = idx[ib + srow];
    const float* src = kbase + (size_t)kr * 512 + sh;
#pragma unroll
    for (int i = 0; i < 8; ++i) vst[i] = ld4(src + 4*i);
  }

  float mx[4][4];
#pragma unroll
  for (int mi = 0; mi < 4; ++mi)
#pragma unroll
    for (int r = 0; r < 4; ++r) mx[mi][r] = -INFINITY;

  for (int tl = 0; tl < 8; ++tl) {
    __syncthreads();
    {  // staged regs -> 3 bf16 planes
#pragma unroll
      for (int e2 = 0; e2 < 4; ++e2) {
        union { bf16x8 v; unsigned short u[8]; } H, M, L;
        float xs[8] = {vst[2*e2].x, vst[2*e2].y, vst[2*e2].z, vst[2*e2].w,
                       vst[2*e2+1].x, vst[2*e2+1].y, vst[2*e2+1].z, vst[2*e2+1].w};
#pragma unroll
        for (int e = 0; e < 8; ++e) tsplit(xs[e], H.u[e], M.u[e], L.u[e]);
        *reinterpret_cast<bf16x8*>(&k3[0][srow][sh + 8*e2]) = H.v;
        *reinterpret_cast<bf16x8*>(&k3[1][srow][sh + 8*e2]) = M.v;
        *reinterpret_cast<bf16x8*>(&k3[2][srow][sh + 8*e2]) = L.v;
      }
    }
    if (tl < 7) {
      const int kr = idx[ib + (tl+1)*128 + srow];
      const float* src = kbase + (size_t)kr * 512 + sh;
#pragma unroll
      for (int i = 0; i < 8; ++i) vst[i] = ld4(src + 4*i);
    }
    __syncthreads();

    for (int n2 = 0; n2 < 4; ++n2) {       // key-column groups of 32
      bf16x8 bf[2][3][2];                  // [ns][plane][kstep]
#pragma unroll
      for (int ns = 0; ns < 2; ++ns)
#pragma unroll
        for (int p = 0; p < 3; ++p)
#pragma unroll
          for (int c = 0; c < 2; ++c)
            bf[ns][p][c] = *reinterpret_cast<const bf16x8*>(&k3[p][n2*32 + ns*16 + lr][c*32 + lg*8]);
#pragma unroll
      for (int mi = 0; mi < 4; ++mi)
#pragma unroll
        for (int ns = 0; ns < 2; ++ns) {
          f32x4 acc = {0.f, 0.f, 0.f, 0.f};
#pragma unroll
          for (int c = 0; c < 2; ++c) acc = __builtin_amdgcn_mfma_f32_16x16x32_bf16(qf[mi][c][0], bf[ns][0][c], acc, 0, 0, 0); // hh
#pragma unroll
          for (int c = 0; c < 2; ++c) acc = __builtin_amdgcn_mfma_f32_16x16x32_bf16(qf[mi][c][0], bf[ns][1][c], acc, 0, 0, 0); // hm
#pragma unroll
          for (int c = 0; c < 2; ++c) acc = __builtin_amdgcn_mfma_f32_16x16x32_bf16(qf[mi][c][1], bf[ns][0][c], acc, 0, 0, 0); // mh
#pragma unroll
          for (int c = 0; c < 2; ++c) acc = __builtin_amdgcn_mfma_f32_16x16x32_bf16(qf[mi][c][1], bf[ns][1][c], acc, 0, 0, 0); // mm
#pragma unroll
          for (int c = 0; c < 2; ++c) acc = __builtin_amdgcn_mfma_f32_16x16x32_bf16(qf[mi][c][0], bf[ns][2][c], acc, 0, 0, 0); // hl
#pragma unroll
          for (int c = 0; c < 2; ++c) acc = __builtin_amdgcn_mfma_f32_16x16x32_bf16(qf[mi][c][2], bf[ns][0][c], acc, 0, 0, 0); // lh
#pragma unroll
          for (int r = 0; r < 4; ++r) mx[mi][r] = fmaxf(mx[mi][r], acc[r]);
        }
    }
  }

  // reduce max across the 16 key-lanes; D: row(q) = lg*4+r, col(key) = lr
#pragma unroll
  for (int mi = 0; mi < 4; ++mi)
#pragma unroll
    for (int r = 0; r < 4; ++r) {
      float v = mx[mi][r];
      v = fmaxf(v, __shfl_xor(v, 1));
      v = fmaxf(v, __shfl_xor(v, 2));
      v = fmaxf(v, __shfl_xor(v, 4));
      v = fmaxf(v, __shfl_xor(v, 8));
      if (lr == 0)
        Mp[ks*32768 + bh*2048 + qt*256 + w*64 + mi*16 + lg*4 + r] = v;
    }
}

// ---------------------------------------------------------------- fused M-finalize + top-40 (stable, == top_k(-M))
__global__ __launch_bounds__(256) void topk_kernel(const float* __restrict__ qp,
                                                   const float* __restrict__ ksum,
                                                   const float* __restrict__ Mp,
                                                   int* __restrict__ Mtop) {
  __shared__ float mv[2048];
  __shared__ float ks_s[64];
  __shared__ float wvs[4];
  __shared__ int   wis[4];
  const int bh = blockIdx.x;
  const int b = bh >> 3, h = bh & 7;
  const int t = threadIdx.x;
  if (t < 64) ks_s[t] = ksum[bh*64 + t];
  __syncthreads();
#pragma unroll
  for (int c = 0; c < 8; ++c) {
    const int qi = c * 256 + t;
    const float* qrow = qp + (size_t)b*BHD + (size_t)h*QHS + (size_t)qi * 64;
    float dot = 0.f;
#pragma unroll
    for (int cc = 0; cc < 16; ++cc) {
      float4 q4 = ld4(qrow + 4 * cc);
      dot += q4.x * ks_s[4*cc + 0];
      dot += q4.y * ks_s[4*cc + 1];
      dot += q4.z * ks_s[4*cc + 2];
      dot += q4.w * ks_s[4*cc + 3];
    }
    mv[qi] = fmaxf(Mp[bh*2048 + qi], Mp[32768 + bh*2048 + qi]) - dot * (1.0f/2048.0f);
  }
  __syncthreads();
  const int wl = t & 63, w = t >> 6;
  for (int it = 0; it < NU; ++it) {
    float bv = mv[t]; int bi = t;
#pragma unroll
    for (int c = 1; c < 8; ++c) {
      const float v = mv[t + 256*c];
      if (v < bv) { bv = v; bi = t + 256*c; }
    }
#pragma unroll
    for (int off = 1; off < 64; off <<= 1) {
      const float ov = __shfl_xor(bv, off);
      const int   oi = __shfl_xor(bi, off);
      if (ov < bv || (ov == bv && oi < bi)) { bv = ov; bi = oi; }
    }
    if (wl == 0) { wvs[w] = bv; wis[w] = bi; }
    __syncthreads();
    if (t == 0) {
      float fv = wvs[0]; int fi = wis[0];
#pragma unroll
      for (int w2 = 1; w2 < 4; ++w2)
        if (wvs[w2] < fv || (wvs[w2] == fv && wis[w2] < fi)) { fv = wvs[w2]; fi = wis[w2]; }
      Mtop[bh*NU + it] = fi;
      mv[fi] = INFINITY;
    }
    __syncthreads();
  }
}

// ---------------------------------------------------------------- flash partials over 128-key slabs
__global__ __launch_bounds__(256) void flash_partial(const float* __restrict__ qp,
                                                     const float* __restrict__ kp,
                                                     const float* __restrict__ vp,
                                                     const int* __restrict__ Mtop,
                                                     float* __restrict__ pm,
                                                     float* __restrict__ pl,
                                                     float* __restrict__ pacc) {
  __shared__ float qr[NU][65];
  __shared__ float kv[64][65];
  __shared__ float sl[NU][65];
  __shared__ float ms[NU], ls[NU], fs[NU];
  const int bid = blockIdx.x;
  const int bh = bid >> 4, kt = bid & 15;
  const int b = bh >> 3, h = bh & 7;
  const int t = threadIdx.x;
  const int g = t >> 6, j = t & 63;
  const int r4 = t >> 2, sub = t & 3;

  {
    const float* qbase = qp + (size_t)b*BHD + (size_t)h*QHS;
#pragma unroll
    for (int r = 0; r < 10; ++r) {
      const int q = g*10 + r;
      qr[q][j] = qbase[(size_t)Mtop[bh*NU + q]*64 + j];
    }
  }
  if (t < NU) { ms[t] = -INFINITY; ls[t] = 0.f; }
  float acc[10];
#pragma unroll
  for (int r = 0; r < 10; ++r) acc[r] = 0.f;

  const float* kbase = kp + (size_t)b*BHD + h*DH;
  const float* vbase = vp + (size_t)b*BHD + h*DH;
  const int srow = t >> 2, scb = (t & 3)*16;

  for (int st = 0; st < 2; ++st) {
    const int kb = kt*128 + st*64;
    __syncthreads();
    {
      const float* src = kbase + (size_t)(kb + srow)*512 + scb;
#pragma unroll
      for (int i = 0; i < 4; ++i) {
        float4 v = ld4(src + 4*i);
        kv[srow][scb + 4*i + 0] = v.x;
        kv[srow][scb + 4*i + 1] = v.y;
        kv[srow][scb + 4*i + 2] = v.z;
        kv[srow][scb + 4*i + 3] = v.w;
      }
    }
    __syncthreads();
    {
      float sv[10];
#pragma unroll
      for (int r = 0; r < 10; ++r) {
        const int q = g*10 + r;
        float s = 0.f;
#pragma unroll 8
        for (int jj = 0; jj < 64; ++jj) s += qr[q][jj]*kv[j][jj];
        sv[r] = s * 0.125f;
      }
#pragma unroll
      for (int r = 0; r < 10; ++r) sl[g*10 + r][j] = sv[r];
    }
    __syncthreads();
    float4 vst[4];
    {
      const float* src = vbase + (size_t)(kb + srow)*512 + scb;
#pragma unroll
      for (int i = 0; i < 4; ++i) vst[i] = ld4(src + 4*i);
    }
    if (r4 < NU) {
      float tm = -INFINITY;
#pragma unroll
      for (int c = 0; c < 16; ++c) tm = fmaxf(tm, sl[r4][sub*16 + c]);
      tm = fmaxf(tm, __shfl_xor(tm, 1));
      tm = fmaxf(tm, __shfl_xor(tm, 2));
      const float nm = fmaxf(ms[r4], tm);
      if (sub == 0) { fs[r4] = expf(ms[r4] - nm); ms[r4] = nm; }
    }
    __syncthreads();
    {
#pragma unroll
      for (int r = 0; r < 10; ++r) {
        const int q = g*10 + r;
        acc[r] *= fs[q];
        sl[q][j] = expf(sl[q][j] - ms[q]);
      }
#pragma unroll
      for (int i = 0; i < 4; ++i) {
        kv[srow][scb + 4*i + 0] = vst[i].x;
        kv[srow][scb + 4*i + 1] = vst[i].y;
        kv[srow][scb + 4*i + 2] = vst[i].z;
        kv[srow][scb + 4*i + 3] = vst[i].w;
      }
    }
    __syncthreads();
    if (r4 < NU) {
      float s = 0.f;
#pragma unroll
      for (int c = 0; c < 16; ++c) s += sl[r4][sub*16 + c];
      s += __shfl_xor(s, 1);
      s += __shfl_xor(s, 2);
      if (sub == 0) ls[r4] = ls[r4]*fs[r4] + s;
    }
    {
#pragma unroll 4
      for (int kk = 0; kk < 64; ++kk) {
        const float vv = kv[kk][j];
#pragma unroll
        for (int r = 0; r < 10; ++r) acc[r] += sl[g*10 + r][kk]*vv;
      }
    }
  }
  __syncthreads();
  const size_t base = (size_t)(bh*16 + kt)*NU;
  if (t < NU) { pm[base + t] = ms[t]; pl[base + t] = ls[t]; }
#pragma unroll
  for (int r = 0; r < 10; ++r)
    pacc[(base + g*10 + r)*64 + j] = acc[r];
}

// ---------------------------------------------------------------- combine 16 partials, write outc (B,40,512)
__global__ __launch_bounds__(256) void flash_combine(const float* __restrict__ pm,
                                                     const float* __restrict__ pl,
                                                     const float* __restrict__ pacc,
                                                     float* __restrict__ outc) {
  const int t = threadIdx.x;
  const int qg = t >> 6, j = t & 63;
  const int bh = blockIdx.x / 10;
  const int q  = (blockIdx.x % 10)*4 + qg;
  const int b = bh >> 3, h = bh & 7;
  float m = -INFINITY;
#pragma unroll
  for (int kt = 0; kt < 16; ++kt) m = fmaxf(m, pm[(size_t)(bh*16 + kt)*NU + q]);
  float Lsum = 0.f, num = 0.f;
#pragma unroll
  for (int kt = 0; kt < 16; ++kt) {
    const size_t base = (size_t)(bh*16 + kt)*NU;
    const float w = expf(pm[base + q] - m);
    Lsum += w * pl[base + q];
    num  += w * pacc[(base + q)*64 + j];
  }
  outc[(size_t)(b*NU + q)*512 + h*64 + j] = num / Lsum;
}

// ---------------------------------------------------------------- Wo GEMM, split-k x4
__global__ __launch_bounds__(256) void wo_gemm(const float* __restrict__ outc,
                                               const float* __restrict__ Wo,
                                               float* __restrict__ pwo) {
  __shared__ __align__(16) float a_t[80][68];
  __shared__ __align__(16) float w_t[64][68];
  const int t = threadIdx.x;
  const int ty = t >> 4, tx = t & 15;
  const int nt = blockIdx.x, ks = blockIdx.y;
  float acc[5][4];
#pragma unroll
  for (int i = 0; i < 5; ++i)
#pragma unroll
    for (int j = 0; j < 4; ++j) acc[i][j] = 0.f;

  for (int c = 0; c < 2; ++c) {
    const int kb = ks*128 + c*64;
    __syncthreads();
#pragma unroll
    for (int i = 0; i < 20; ++i) {
      const int fi = t + 256*i;
      const int row = fi >> 6, col = fi & 63;
      a_t[row][col] = outc[(size_t)row*512 + kb + col];
    }
#pragma unroll
    for (int i = 0; i < 16; ++i) {
      const int fi = t + 256*i;
      const int row = fi >> 6, col = fi & 63;
      w_t[row][col] = Wo[(size_t)(nt*64 + row)*512 + kb + col];
    }
    __syncthreads();
    for (int gq = 0; gq < 16; ++gq) {
      float4 av[5], wv[4];
#pragma unroll
      for (int i = 0; i < 5; ++i) av[i] = *reinterpret_cast<const float4*>(&a_t[ty + 16*i][4*gq]);
#pragma unroll
      for (int j = 0; j < 4; ++j) wv[j] = *reinterpret_cast<const float4*>(&w_t[tx + 16*j][4*gq]);
#pragma unroll
      for (int i = 0; i < 5; ++i)
#pragma unroll
        for (int j = 0; j < 4; ++j) {
          acc[i][j] += av[i].x * wv[j].x;
          acc[i][j] += av[i].y * wv[j].y;
          acc[i][j] += av[i].z * wv[j].z;
          acc[i][j] += av[i].w * wv[j].w;
        }
    }
  }
#pragma unroll
  for (int i = 0; i < 5; ++i)
#pragma unroll
    for (int j = 0; j < 4; ++j)
      pwo[ks*40960 + (size_t)(ty + 16*i)*512 + nt*64 + tx + 16*j] = acc[i][j];
}

__global__ __launch_bounds__(256) void wo_combine(const float* __restrict__ pwo,
                                                  const float* __restrict__ bo,
                                                  float* __restrict__ out) {
  const int gi = blockIdx.x*256 + threadIdx.x;
  const float4* p = reinterpret_cast<const float4*>(pwo);
  const float4 a = p[gi], b4 = p[10240 + gi], c4 = p[20480 + gi], d4 = p[30720 + gi];
  const float4 bb = ld4(bo + 4*(gi & 127));
  float4 o;
  o.x = a.x + b4.x + c4.x + d4.x + bb.x;
  o.y = a.y + b4.y + c4.y + d4.y + bb.y;
  o.z = a.z + b4.z + c4.z + d4.z + bb.z;
  o.w = a.w + b4.w + c4.w + d4.w + bb.w;
  reinterpret_cast<float4*>(out)[gi] = o;
}

// ----------------------------------------------------------------
extern "C" void kernel_launch(void* const* d_in, const int* in_sizes, int n_in,
                              void* d_out, int out_size, void* d_ws, size_t ws_size,
                              hipStream_t stream) {
  const float* q  = (const float*)d_in[0];
  const float* k  = (const float*)d_in[1];
  const float* v  = (const float*)d_in[2];
  const float* Wq = (const float*)d_in[3];
  const float* bq = (const float*)d_in[4];
  const float* Wk = (const float*)d_in[5];
  const float* bk = (const float*)d_in[6];
  const float* Wv = (const float*)d_in[7];
  const float* bv = (const float*)d_in[8];
  const float* Wo = (const float*)d_in[9];
  const float* bo = (const float*)d_in[10];
  const int*  idx = (const int*)d_in[11];

  float* ws   = (float*)d_ws;
  float* qp   = ws;                        // 2,097,152
  float* kp   = ws + 2097152;              // 2,097,152
  float* vp   = ws + 4194304;              // 2,097,152
  float* ksum = ws + 6291456;              // 1,024
  int*   Mtop = (int*)(ws + 6292480);      // 640
  float* pm   = ws + 6293120;              // 10,240
  float* pl   = ws + 6303360;              // 10,240
  float* pacc = ws + 6313600;              // 655,360
  float* outc = ws + 6968960;              // 40,960
  // time-disjoint aliases:
  float* Mp   = pm;                        // 65,536 needed; dead before flash_partial
  float* pwo  = pm;                        // 163,840 needed; written after flash_combine reads pm/pl/pacc

  const dim3 blk(256);
  proj_mfma<<<dim3(32, 4, 3), blk, 0, stream>>>(q, k, v, Wq, Wk, Wv, bq, bk, bv, qp, kp, vp);
  ksum_kernel<<<dim3(16), dim3(1024), 0, stream>>>(kp, idx, ksum);
  m_kernel<<<dim3(256), blk, 0, stream>>>(qp, kp, idx, Mp);
  topk_kernel<<<dim3(16), blk, 0, stream>>>(qp, ksum, Mp, Mtop);
  flash_partial<<<dim3(256), blk, 0, stream>>>(qp, kp, vp, Mtop, pm, pl, pacc);
  flash_combine<<<dim3(160), blk, 0, stream>>>(pm, pl, pacc, outc);
  wo_gemm<<<dim3(8, 4), blk, 0, stream>>>(outc, Wo, pwo);
  wo_combine<<<dim3(40), blk, 0, stream>>>(pwo, bo, (float*)d_out);
}

// Round 5
// 199.051 us; speedup vs baseline: 2.9959x; 1.1381x over previous
//
#include <hip/hip_runtime.h>
#include <math.h>

#define B_ 2
#define L_ 2048
#define D_ 512
#define H_ 8
#define DH 64
#define NS 2048   // U_part (sampled keys)
#define NU 40     // u (selected queries)
#define BHD (L_*D_)        // per-batch stride of qp/kp/vp
#define QHS (L_*DH)        // per-head stride inside qh view

typedef __attribute__((ext_vector_type(8))) short bf16x8;
typedef __attribute__((ext_vector_type(4))) float f32x4;

__device__ inline float4 ld4(const float* p) { return *reinterpret_cast<const float4*>(p); }

// truncation split: x = h + m + r, all bf16-representable (exact truncations),
// |m| <= 2^-8|x|, |r_bf| captures to 2^-24|x|. 6-product MFMA == fp32-class dot.
__device__ inline unsigned short hi16(float x) { return (unsigned short)(__float_as_uint(x) >> 16); }
__device__ inline float trunchf(float x) { return __uint_as_float(__float_as_uint(x) & 0xFFFF0000u); }
__device__ inline void tsplit(float x, unsigned short& hs, unsigned short& ms, unsigned short& ls) {
  float h = trunchf(x); hs = hi16(x);
  float r = x - h;                 // exact
  float m = trunchf(r); ms = hi16(r);
  float r2 = r - m;                // exact
  ls = hi16(r2);
}

// ---------------------------------------------------------------- projection GEMM, split-bf16 MFMA
__global__ __launch_bounds__(256) void proj_mfma(
    const float* __restrict__ qa, const float* __restrict__ ka, const float* __restrict__ va,
    const float* __restrict__ Wq, const float* __restrict__ Wk, const float* __restrict__ Wv,
    const float* __restrict__ bq, const float* __restrict__ bk, const float* __restrict__ bv,
    float* __restrict__ qp, float* __restrict__ kp, float* __restrict__ vp)
{
  __shared__ __align__(16) unsigned short a3[3][128][36];
  __shared__ __align__(16) unsigned short w3[3][128][36];
  const int t = threadIdx.x;
  const int mat = blockIdx.z;
  const float* A    = (mat == 0) ? qa : (mat == 1) ? ka : va;
  const float* W    = (mat == 0) ? Wq : (mat == 1) ? Wk : Wv;
  const float* bias = (mat == 0) ? bq : (mat == 1) ? bk : bv;
  float* C          = (mat == 0) ? qp : (mat == 1) ? kp : vp;
  const int m0 = blockIdx.x * 128, n0 = blockIdx.y * 128;
  const int w = t >> 6, l = t & 63;
  const int wm = w >> 1, wn = w & 1;
  const int lr = l & 15, lg = l >> 4;
  const int srow = t >> 1, sc0 = (t & 1) * 16;

  f32x4 acc[4][4];
#pragma unroll
  for (int i = 0; i < 4; ++i)
#pragma unroll
    for (int j = 0; j < 4; ++j) acc[i][j] = (f32x4){0.f, 0.f, 0.f, 0.f};

  for (int kc = 0; kc < 16; ++kc) {
    const int kb = kc * 32;
    __syncthreads();
    {
      const float* src = A + (size_t)(m0 + srow) * 512 + kb + sc0;
      float xs[16];
#pragma unroll
      for (int i = 0; i < 4; ++i) {
        float4 v4 = ld4(src + 4*i);
        xs[4*i] = v4.x; xs[4*i+1] = v4.y; xs[4*i+2] = v4.z; xs[4*i+3] = v4.w;
      }
#pragma unroll
      for (int hh = 0; hh < 2; ++hh) {
        union { bf16x8 v; unsigned short u[8]; } H, M, L;
#pragma unroll
        for (int e = 0; e < 8; ++e) tsplit(xs[hh*8 + e], H.u[e], M.u[e], L.u[e]);
        *reinterpret_cast<bf16x8*>(&a3[0][srow][sc0 + 8*hh]) = H.v;
        *reinterpret_cast<bf16x8*>(&a3[1][srow][sc0 + 8*hh]) = M.v;
        *reinterpret_cast<bf16x8*>(&a3[2][srow][sc0 + 8*hh]) = L.v;
      }
    }
    {
      const float* src = W + (size_t)(n0 + srow) * 512 + kb + sc0;
      float xs[16];
#pragma unroll
      for (int i = 0; i < 4; ++i) {
        float4 v4 = ld4(src + 4*i);
        xs[4*i] = v4.x; xs[4*i+1] = v4.y; xs[4*i+2] = v4.z; xs[4*i+3] = v4.w;
      }
#pragma unroll
      for (int hh = 0; hh < 2; ++hh) {
        union { bf16x8 v; unsigned short u[8]; } H, M, L;
#pragma unroll
        for (int e = 0; e < 8; ++e) tsplit(xs[hh*8 + e], H.u[e], M.u[e], L.u[e]);
        *reinterpret_cast<bf16x8*>(&w3[0][srow][sc0 + 8*hh]) = H.v;
        *reinterpret_cast<bf16x8*>(&w3[1][srow][sc0 + 8*hh]) = M.v;
        *reinterpret_cast<bf16x8*>(&w3[2][srow][sc0 + 8*hh]) = L.v;
      }
    }
    __syncthreads();

    bf16x8 af[3][4], bf[3][4];
#pragma unroll
    for (int p = 0; p < 3; ++p)
#pragma unroll
      for (int mi = 0; mi < 4; ++mi)
        af[p][mi] = *reinterpret_cast<const bf16x8*>(&a3[p][wm*64 + mi*16 + lr][lg*8]);
#pragma unroll
    for (int p = 0; p < 3; ++p)
#pragma unroll
      for (int ni = 0; ni < 4; ++ni)
        bf[p][ni] = *reinterpret_cast<const bf16x8*>(&w3[p][wn*64 + ni*16 + lr][lg*8]);
#pragma unroll
    for (int mi = 0; mi < 4; ++mi)
#pragma unroll
      for (int ni = 0; ni < 4; ++ni) {
        acc[mi][ni] = __builtin_amdgcn_mfma_f32_16x16x32_bf16(af[0][mi], bf[0][ni], acc[mi][ni], 0, 0, 0); // hh
        acc[mi][ni] = __builtin_amdgcn_mfma_f32_16x16x32_bf16(af[0][mi], bf[1][ni], acc[mi][ni], 0, 0, 0); // hm
        acc[mi][ni] = __builtin_amdgcn_mfma_f32_16x16x32_bf16(af[1][mi], bf[0][ni], acc[mi][ni], 0, 0, 0); // mh
        acc[mi][ni] = __builtin_amdgcn_mfma_f32_16x16x32_bf16(af[1][mi], bf[1][ni], acc[mi][ni], 0, 0, 0); // mm
        acc[mi][ni] = __builtin_amdgcn_mfma_f32_16x16x32_bf16(af[0][mi], bf[2][ni], acc[mi][ni], 0, 0, 0); // hl
        acc[mi][ni] = __builtin_amdgcn_mfma_f32_16x16x32_bf16(af[2][mi], bf[0][ni], acc[mi][ni], 0, 0, 0); // lh
      }
  }
#pragma unroll
  for (int mi = 0; mi < 4; ++mi)
#pragma unroll
    for (int ni = 0; ni < 4; ++ni) {
      const int gn = n0 + wn*64 + ni*16 + lr;
      const float bv_ = bias[gn];
#pragma unroll
      for (int r = 0; r < 4; ++r) {
        const int gm = m0 + wm*64 + mi*16 + lg*4 + r;
        C[(size_t)gm * 512 + gn] = acc[mi][ni][r] + bv_;
      }
    }
}

// ---------------------------------------------------------------- Ksum[bh][j] = sum_s kp[b, idx[s], h*64+j]
__global__ __launch_bounds__(1024) void ksum_kernel(const float* __restrict__ kp,
                                                    const int* __restrict__ idx,
                                                    float* __restrict__ ksum) {
  __shared__ float part[16][64];
  const int bh = blockIdx.x;
  const int b = bh >> 3, h = bh & 7;
  const int t = threadIdx.x;
  const int sg = t >> 6, j = t & 63;
  const float* kbase = kp + (size_t)b*BHD + h*DH;
  float a = 0.f;
  for (int s = sg*128; s < sg*128 + 128; ++s)
    a += kbase[(size_t)idx[s]*512 + j];
  part[sg][j] = a;
  __syncthreads();
  if (t < 64) {
    float s = 0.f;
#pragma unroll
    for (int i = 0; i < 16; ++i) s += part[i][t];
    ksum[bh*64 + t] = s;
  }
}

// ---------------------------------------------------------------- Mp[ks][bh][q] = max over 1024 sampled keys of q.k
__global__ __launch_bounds__(256) void m_kernel(const float* __restrict__ qp,
                                                const float* __restrict__ kp,
                                                const int* __restrict__ idx,
                                                float* __restrict__ Mp) {
  __shared__ __align__(16) unsigned short k3[3][128][72];
  const int t = threadIdx.x;
  const int bid = blockIdx.x;
  const int bh = bid >> 4, qt = (bid >> 1) & 7, ks = bid & 1;
  const int b = bh >> 3, h = bh & 7;
  const int w = t >> 6, l = t & 63;
  const int lr = l & 15;
  const int lg = l >> 4;

  bf16x8 qf[4][2][3];
  {
    const float* qbase = qp + (size_t)b*BHD + (size_t)h*QHS + (size_t)(qt*256 + w*64 + lr) * 64 + lg*8;
#pragma unroll
    for (int mi = 0; mi < 4; ++mi)
#pragma unroll
      for (int c = 0; c < 2; ++c) {
        const float* src = qbase + mi*16*64 + c*32;
        float4 x0 = ld4(src), x1 = ld4(src + 4);
        float xs[8] = {x0.x, x0.y, x0.z, x0.w, x1.x, x1.y, x1.z, x1.w};
        union { bf16x8 v; unsigned short u[8]; } H, M, L;
#pragma unroll
        for (int e = 0; e < 8; ++e) tsplit(xs[e], H.u[e], M.u[e], L.u[e]);
        qf[mi][c][0] = H.v; qf[mi][c][1] = M.v; qf[mi][c][2] = L.v;
      }
  }

  const float* kbase = kp + (size_t)b*BHD + h*DH;
  const int ib = ks * 1024;
  const int srow = t >> 1, sh = (t & 1) * 32;

  float4 vst[8];
  {
    const int kr = idx[ib + srow];
    const float* src = kbase + (size_t)kr * 512 + sh;
#pragma unroll
    for (int i = 0; i < 8; ++i) vst[i] = ld4(src + 4*i);
  }

  float mx[4][4];
#pragma unroll
  for (int mi = 0; mi < 4; ++mi)
#pragma unroll
    for (int r = 0; r < 4; ++r) mx[mi][r] = -INFINITY;

  for (int tl = 0; tl < 8; ++tl) {
    __syncthreads();
    {
#pragma unroll
      for (int e2 = 0; e2 < 4; ++e2) {
        union { bf16x8 v; unsigned short u[8]; } H, M, L;
        float xs[8] = {vst[2*e2].x, vst[2*e2].y, vst[2*e2].z, vst[2*e2].w,
                       vst[2*e2+1].x, vst[2*e2+1].y, vst[2*e2+1].z, vst[2*e2+1].w};
#pragma unroll
        for (int e = 0; e < 8; ++e) tsplit(xs[e], H.u[e], M.u[e], L.u[e]);
        *reinterpret_cast<bf16x8*>(&k3[0][srow][sh + 8*e2]) = H.v;
        *reinterpret_cast<bf16x8*>(&k3[1][srow][sh + 8*e2]) = M.v;
        *reinterpret_cast<bf16x8*>(&k3[2][srow][sh + 8*e2]) = L.v;
      }
    }
    if (tl < 7) {
      const int kr = idx[ib + (tl+1)*128 + srow];
      const float* src = kbase + (size_t)kr * 512 + sh;
#pragma unroll
      for (int i = 0; i < 8; ++i) vst[i] = ld4(src + 4*i);
    }
    __syncthreads();

    for (int n2 = 0; n2 < 4; ++n2) {
      bf16x8 bf[2][3][2];
#pragma unroll
      for (int ns = 0; ns < 2; ++ns)
#pragma unroll
        for (int p = 0; p < 3; ++p)
#pragma unroll
          for (int c = 0; c < 2; ++c)
            bf[ns][p][c] = *reinterpret_cast<const bf16x8*>(&k3[p][n2*32 + ns*16 + lr][c*32 + lg*8]);
#pragma unroll
      for (int mi = 0; mi < 4; ++mi)
#pragma unroll
        for (int ns = 0; ns < 2; ++ns) {
          f32x4 acc = {0.f, 0.f, 0.f, 0.f};
#pragma unroll
          for (int c = 0; c < 2; ++c) acc = __builtin_amdgcn_mfma_f32_16x16x32_bf16(qf[mi][c][0], bf[ns][0][c], acc, 0, 0, 0); // hh
#pragma unroll
          for (int c = 0; c < 2; ++c) acc = __builtin_amdgcn_mfma_f32_16x16x32_bf16(qf[mi][c][0], bf[ns][1][c], acc, 0, 0, 0); // hm
#pragma unroll
          for (int c = 0; c < 2; ++c) acc = __builtin_amdgcn_mfma_f32_16x16x32_bf16(qf[mi][c][1], bf[ns][0][c], acc, 0, 0, 0); // mh
#pragma unroll
          for (int c = 0; c < 2; ++c) acc = __builtin_amdgcn_mfma_f32_16x16x32_bf16(qf[mi][c][1], bf[ns][1][c], acc, 0, 0, 0); // mm
#pragma unroll
          for (int c = 0; c < 2; ++c) acc = __builtin_amdgcn_mfma_f32_16x16x32_bf16(qf[mi][c][0], bf[ns][2][c], acc, 0, 0, 0); // hl
#pragma unroll
          for (int c = 0; c < 2; ++c) acc = __builtin_amdgcn_mfma_f32_16x16x32_bf16(qf[mi][c][2], bf[ns][0][c], acc, 0, 0, 0); // lh
#pragma unroll
          for (int r = 0; r < 4; ++r) mx[mi][r] = fmaxf(mx[mi][r], acc[r]);
        }
    }
  }

#pragma unroll
  for (int mi = 0; mi < 4; ++mi)
#pragma unroll
    for (int r = 0; r < 4; ++r) {
      float v = mx[mi][r];
      v = fmaxf(v, __shfl_xor(v, 1));
      v = fmaxf(v, __shfl_xor(v, 2));
      v = fmaxf(v, __shfl_xor(v, 4));
      v = fmaxf(v, __shfl_xor(v, 8));
      if (lr == 0)
        Mp[ks*32768 + bh*2048 + qt*256 + w*64 + mi*16 + lg*4 + r] = v;
    }
}

// ---------------------------------------------------------------- fused M-finalize + top-40 via radix-select
// Exactly reproduces jax.lax.top_k(-M, 40): ascending (M, index) order, lower index first on ties.
__global__ __launch_bounds__(256) void topk_kernel(const float* __restrict__ qp,
                                                   const float* __restrict__ ksum,
                                                   const float* __restrict__ Mp,
                                                   int* __restrict__ Mtop) {
  __shared__ float ks_s[64];
  __shared__ unsigned hist[256];
  __shared__ int wsum[4];
  __shared__ unsigned bitmap[64];
  __shared__ unsigned long long comb[NU];
  __shared__ int s_sel, s_rem, s_cnt;
  const int bh = blockIdx.x;
  const int b = bh >> 3, h = bh & 7;
  const int t = threadIdx.x;
  if (t < 64) ks_s[t] = ksum[bh*64 + t];
  __syncthreads();

  // compute M for 8 elements/thread, map to ascending-sortable uint32 keys
  unsigned mykey[8];
#pragma unroll
  for (int c = 0; c < 8; ++c) {
    const int qi = c * 256 + t;
    const float* qrow = qp + (size_t)b*BHD + (size_t)h*QHS + (size_t)qi * 64;
    float dot = 0.f;
#pragma unroll
    for (int cc = 0; cc < 16; ++cc) {
      float4 q4 = ld4(qrow + 4 * cc);
      dot += q4.x * ks_s[4*cc + 0];
      dot += q4.y * ks_s[4*cc + 1];
      dot += q4.z * ks_s[4*cc + 2];
      dot += q4.w * ks_s[4*cc + 3];
    }
    const float m = fmaxf(Mp[bh*2048 + qi], Mp[32768 + bh*2048 + qi]) - dot * (1.0f/2048.0f);
    const unsigned u = __float_as_uint(m);
    mykey[c] = (u >> 31) ? ~u : (u | 0x80000000u);
  }

  // 4-pass MSB-first radix select: find key T of the 40th smallest, rem = #take among ==T
  unsigned prefMask = 0u, prefVal = 0u;
  int rem = NU;
  for (int shift = 24; shift >= 0; shift -= 8) {
    hist[t] = 0;
    __syncthreads();
#pragma unroll
    for (int c = 0; c < 8; ++c) {
      const unsigned key = mykey[c];
      if ((key & prefMask) == prefVal)
        atomicAdd(&hist[(key >> shift) & 255], 1u);
    }
    __syncthreads();
    // exclusive scan of 256 bins (4 waves)
    const int binc = (int)hist[t];
    int inc = binc;
#pragma unroll
    for (int off = 1; off < 64; off <<= 1) {
      const int nb = __shfl_up(inc, off);
      if ((t & 63) >= off) inc += nb;
    }
    if ((t & 63) == 63) wsum[t >> 6] = inc;
    __syncthreads();
    int wadd = 0;
    for (int w2 = 0; w2 < (t >> 6); ++w2) wadd += wsum[w2];
    const int incl = inc + wadd;
    const int excl = incl - binc;
    if (excl < rem && rem <= incl) { s_sel = t; s_rem = rem - excl; }
    __syncthreads();
    prefVal |= ((unsigned)s_sel) << shift;
    prefMask |= 0xFFu << shift;
    rem = s_rem;
    __syncthreads();
  }
  const unsigned T = prefVal;

  // collect: key < T appended unordered; key == T via bitmap (lowest indices first)
  if (t < 64) bitmap[t] = 0;
  if (t == 0) s_cnt = 0;
  __syncthreads();
#pragma unroll
  for (int c = 0; c < 8; ++c) {
    const unsigned key = mykey[c];
    const int qi = c * 256 + t;
    if (key < T) {
      const int pos = atomicAdd(&s_cnt, 1);
      comb[pos] = ((unsigned long long)key << 11) | (unsigned)qi;
    } else if (key == T) {
      atomicOr(&bitmap[qi >> 5], 1u << (qi & 31));
    }
  }
  __syncthreads();
  if (t == 0) {
    int need = rem, cpos = s_cnt;
    for (int wd = 0; wd < 64 && need > 0; ++wd) {
      unsigned bits = bitmap[wd];
      while (bits && need > 0) {
        const int bit = __ffs(bits) - 1;
        bits &= bits - 1;
        comb[cpos++] = ((unsigned long long)T << 11) | (unsigned)(wd*32 + bit);
        --need;
      }
    }
  }
  __syncthreads();

  // rank-sort the 40 combs with one wave (ascending (key, idx))
  if (t < 64) {
    const unsigned long long mine = (t < NU) ? comb[t] : ~0ULL;
    int rank = 0;
#pragma unroll
    for (int step = 1; step < 64; ++step) {
      const unsigned long long other = __shfl(mine, (t + step) & 63);
      rank += (other < mine) ? 1 : 0;
    }
    if (t < NU) Mtop[bh*NU + rank] = (int)(mine & 0x7FFu);
  }
}

// ---------------------------------------------------------------- flash partials over 128-key slabs
__global__ __launch_bounds__(256) void flash_partial(const float* __restrict__ qp,
                                                     const float* __restrict__ kp,
                                                     const float* __restrict__ vp,
                                                     const int* __restrict__ Mtop,
                                                     float* __restrict__ pm,
                                                     float* __restrict__ pl,
                                                     float* __restrict__ pacc) {
  __shared__ float qr[NU][65];
  __shared__ float kv[64][65];
  __shared__ float sl[NU][65];
  __shared__ float ms[NU], ls[NU], fs[NU];
  const int bid = blockIdx.x;
  const int bh = bid >> 4, kt = bid & 15;
  const int b = bh >> 3, h = bh & 7;
  const int t = threadIdx.x;
  const int g = t >> 6, j = t & 63;
  const int r4 = t >> 2, sub = t & 3;

  {
    const float* qbase = qp + (size_t)b*BHD + (size_t)h*QHS;
#pragma unroll
    for (int r = 0; r < 10; ++r) {
      const int q = g*10 + r;
      qr[q][j] = qbase[(size_t)Mtop[bh*NU + q]*64 + j];
    }
  }
  if (t < NU) { ms[t] = -INFINITY; ls[t] = 0.f; }
  float acc[10];
#pragma unroll
  for (int r = 0; r < 10; ++r) acc[r] = 0.f;

  const float* kbase = kp + (size_t)b*BHD + h*DH;
  const float* vbase = vp + (size_t)b*BHD + h*DH;
  const int srow = t >> 2, scb = (t & 3)*16;

  for (int st = 0; st < 2; ++st) {
    const int kb = kt*128 + st*64;
    __syncthreads();
    {
      const float* src = kbase + (size_t)(kb + srow)*512 + scb;
#pragma unroll
      for (int i = 0; i < 4; ++i) {
        float4 v = ld4(src + 4*i);
        kv[srow][scb + 4*i + 0] = v.x;
        kv[srow][scb + 4*i + 1] = v.y;
        kv[srow][scb + 4*i + 2] = v.z;
        kv[srow][scb + 4*i + 3] = v.w;
      }
    }
    __syncthreads();
    {
      float sv[10];
#pragma unroll
      for (int r = 0; r < 10; ++r) {
        const int q = g*10 + r;
        float s = 0.f;
#pragma unroll 8
        for (int jj = 0; jj < 64; ++jj) s += qr[q][jj]*kv[j][jj];
        sv[r] = s * 0.125f;
      }
#pragma unroll
      for (int r = 0; r < 10; ++r) sl[g*10 + r][j] = sv[r];
    }
    __syncthreads();
    float4 vst[4];
    {
      const float* src = vbase + (size_t)(kb + srow)*512 + scb;
#pragma unroll
      for (int i = 0; i < 4; ++i) vst[i] = ld4(src + 4*i);
    }
    if (r4 < NU) {
      float tm = -INFINITY;
#pragma unroll
      for (int c = 0; c < 16; ++c) tm = fmaxf(tm, sl[r4][sub*16 + c]);
      tm = fmaxf(tm, __shfl_xor(tm, 1));
      tm = fmaxf(tm, __shfl_xor(tm, 2));
      const float nm = fmaxf(ms[r4], tm);
      if (sub == 0) { fs[r4] = expf(ms[r4] - nm); ms[r4] = nm; }
    }
    __syncthreads();
    {
#pragma unroll
      for (int r = 0; r < 10; ++r) {
        const int q = g*10 + r;
        acc[r] *= fs[q];
        sl[q][j] = expf(sl[q][j] - ms[q]);
      }
#pragma unroll
      for (int i = 0; i < 4; ++i) {
        kv[srow][scb + 4*i + 0] = vst[i].x;
        kv[srow][scb + 4*i + 1] = vst[i].y;
        kv[srow][scb + 4*i + 2] = vst[i].z;
        kv[srow][scb + 4*i + 3] = vst[i].w;
      }
    }
    __syncthreads();
    if (r4 < NU) {
      float s = 0.f;
#pragma unroll
      for (int c = 0; c < 16; ++c) s += sl[r4][sub*16 + c];
      s += __shfl_xor(s, 1);
      s += __shfl_xor(s, 2);
      if (sub == 0) ls[r4] = ls[r4]*fs[r4] + s;
    }
    {
#pragma unroll 4
      for (int kk = 0; kk < 64; ++kk) {
        const float vv = kv[kk][j];
#pragma unroll
        for (int r = 0; r < 10; ++r) acc[r] += sl[g*10 + r][kk]*vv;
      }
    }
  }
  __syncthreads();
  const size_t base = (size_t)(bh*16 + kt)*NU;
  if (t < NU) { pm[base + t] = ms[t]; pl[base + t] = ls[t]; }
#pragma unroll
  for (int r = 0; r < 10; ++r)
    pacc[(base + g*10 + r)*64 + j] = acc[r];
}

// ---------------------------------------------------------------- combine 16 partials, write outc (B,40,512)
__global__ __launch_bounds__(256) void flash_combine(const float* __restrict__ pm,
                                                     const float* __restrict__ pl,
                                                     const float* __restrict__ pacc,
                                                     float* __restrict__ outc) {
  const int t = threadIdx.x;
  const int qg = t >> 6, j = t & 63;
  const int bh = blockIdx.x / 10;
  const int q  = (blockIdx.x % 10)*4 + qg;
  const int b = bh >> 3, h = bh & 7;
  float m = -INFINITY;
#pragma unroll
  for (int kt = 0; kt < 16; ++kt) m = fmaxf(m, pm[(size_t)(bh*16 + kt)*NU + q]);
  float Lsum = 0.f, num = 0.f;
#pragma unroll
  for (int kt = 0; kt < 16; ++kt) {
    const size_t base = (size_t)(bh*16 + kt)*NU;
    const float w = expf(pm[base + q] - m);
    Lsum += w * pl[base + q];
    num  += w * pacc[(base + q)*64 + j];
  }
  outc[(size_t)(b*NU + q)*512 + h*64 + j] = num / Lsum;
}

// ---------------------------------------------------------------- Wo GEMM, split-k x4
__global__ __launch_bounds__(256) void wo_gemm(const float* __restrict__ outc,
                                               const float* __restrict__ Wo,
                                               float* __restrict__ pwo) {
  __shared__ __align__(16) float a_t[80][68];
  __shared__ __align__(16) float w_t[64][68];
  const int t = threadIdx.x;
  const int ty = t >> 4, tx = t & 15;
  const int nt = blockIdx.x, ks = blockIdx.y;
  float acc[5][4];
#pragma unroll
  for (int i = 0; i < 5; ++i)
#pragma unroll
    for (int j = 0; j < 4; ++j) acc[i][j] = 0.f;

  for (int c = 0; c < 2; ++c) {
    const int kb = ks*128 + c*64;
    __syncthreads();
#pragma unroll
    for (int i = 0; i < 20; ++i) {
      const int fi = t + 256*i;
      const int row = fi >> 6, col = fi & 63;
      a_t[row][col] = outc[(size_t)row*512 + kb + col];
    }
#pragma unroll
    for (int i = 0; i < 16; ++i) {
      const int fi = t + 256*i;
      const int row = fi >> 6, col = fi & 63;
      w_t[row][col] = Wo[(size_t)(nt*64 + row)*512 + kb + col];
    }
    __syncthreads();
    for (int gq = 0; gq < 16; ++gq) {
      float4 av[5], wv[4];
#pragma unroll
      for (int i = 0; i < 5; ++i) av[i] = *reinterpret_cast<const float4*>(&a_t[ty + 16*i][4*gq]);
#pragma unroll
      for (int j = 0; j < 4; ++j) wv[j] = *reinterpret_cast<const float4*>(&w_t[tx + 16*j][4*gq]);
#pragma unroll
      for (int i = 0; i < 5; ++i)
#pragma unroll
        for (int j = 0; j < 4; ++j) {
          acc[i][j] += av[i].x * wv[j].x;
          acc[i][j] += av[i].y * wv[j].y;
          acc[i][j] += av[i].z * wv[j].z;
          acc[i][j] += av[i].w * wv[j].w;
        }
    }
  }
#pragma unroll
  for (int i = 0; i < 5; ++i)
#pragma unroll
    for (int j = 0; j < 4; ++j)
      pwo[ks*40960 + (size_t)(ty + 16*i)*512 + nt*64 + tx + 16*j] = acc[i][j];
}

__global__ __launch_bounds__(256) void wo_combine(const float* __restrict__ pwo,
                                                  const float* __restrict__ bo,
                                                  float* __restrict__ out) {
  const int gi = blockIdx.x*256 + threadIdx.x;
  const float4* p = reinterpret_cast<const float4*>(pwo);
  const float4 a = p[gi], b4 = p[10240 + gi], c4 = p[20480 + gi], d4 = p[30720 + gi];
  const float4 bb = ld4(bo + 4*(gi & 127));
  float4 o;
  o.x = a.x + b4.x + c4.x + d4.x + bb.x;
  o.y = a.y + b4.y + c4.y + d4.y + bb.y;
  o.z = a.z + b4.z + c4.z + d4.z + bb.z;
  o.w = a.w + b4.w + c4.w + d4.w + bb.w;
  reinterpret_cast<float4*>(out)[gi] = o;
}

// ----------------------------------------------------------------
extern "C" void kernel_launch(void* const* d_in, const int* in_sizes, int n_in,
                              void* d_out, int out_size, void* d_ws, size_t ws_size,
                              hipStream_t stream) {
  const float* q  = (const float*)d_in[0];
  const float* k  = (const float*)d_in[1];
  const float* v  = (const float*)d_in[2];
  const float* Wq = (const float*)d_in[3];
  const float* bq = (const float*)d_in[4];
  const float* Wk = (const float*)d_in[5];
  const float* bk = (const float*)d_in[6];
  const float* Wv = (const float*)d_in[7];
  const float* bv = (const float*)d_in[8];
  const float* Wo = (const float*)d_in[9];
  const float* bo = (const float*)d_in[10];
  const int*  idx = (const int*)d_in[11];

  float* ws   = (float*)d_ws;
  float* qp   = ws;                        // 2,097,152
  float* kp   = ws + 2097152;              // 2,097,152
  float* vp   = ws + 4194304;              // 2,097,152
  float* ksum = ws + 6291456;              // 1,024
  int*   Mtop = (int*)(ws + 6292480);      // 640
  float* pm   = ws + 6293120;              // 10,240
  float* pl   = ws + 6303360;              // 10,240
  float* pacc = ws + 6313600;              // 655,360
  float* outc = ws + 6968960;              // 40,960
  // time-disjoint aliases:
  float* Mp   = pm;                        // 65,536 needed; dead before flash_partial
  float* pwo  = pm;                        // 163,840 needed; written after flash_combine reads pm/pl/pacc

  const dim3 blk(256);
  proj_mfma<<<dim3(32, 4, 3), blk, 0, stream>>>(q, k, v, Wq, Wk, Wv, bq, bk, bv, qp, kp, vp);
  ksum_kernel<<<dim3(16), dim3(1024), 0, stream>>>(kp, idx, ksum);
  m_kernel<<<dim3(256), blk, 0, stream>>>(qp, kp, idx, Mp);
  topk_kernel<<<dim3(16), blk, 0, stream>>>(qp, ksum, Mp, Mtop);
  flash_partial<<<dim3(256), blk, 0, stream>>>(qp, kp, vp, Mtop, pm, pl, pacc);
  flash_combine<<<dim3(160), blk, 0, stream>>>(pm, pl, pacc, outc);
  wo_gemm<<<dim3(8, 4), blk, 0, stream>>>(outc, Wo, pwo);
  wo_combine<<<dim3(40), blk, 0, stream>>>(pwo, bo, (float*)d_out);
}

// Round 6
// 196.158 us; speedup vs baseline: 3.0401x; 1.0147x over previous
//
#include <hip/hip_runtime.h>
#include <math.h>

#define B_ 2
#define L_ 2048
#define D_ 512
#define H_ 8
#define DH 64
#define NS 2048   // U_part (sampled keys)
#define NU 40     // u (selected queries)
#define BHD (L_*D_)        // per-batch stride of qp/kp/vp
#define QHS (L_*DH)        // per-head stride inside qh view
#define WSPM 786432        // ushorts per mat in the W-split buffer

typedef __attribute__((ext_vector_type(8))) short bf16x8;
typedef __attribute__((ext_vector_type(4))) float f32x4;

__device__ inline float4 ld4(const float* p) { return *reinterpret_cast<const float4*>(p); }

// truncation split: x = h + m + r, all bf16-representable (exact truncations).
// 6-product MFMA (hh,hm,mh,mm,hl,lh) == fp32-class dot.
__device__ inline unsigned short hi16(float x) { return (unsigned short)(__float_as_uint(x) >> 16); }
__device__ inline float trunchf(float x) { return __uint_as_float(__float_as_uint(x) & 0xFFFF0000u); }
__device__ inline void tsplit(float x, unsigned short& hs, unsigned short& ms, unsigned short& ls) {
  float h = trunchf(x); hs = hi16(x);
  float r = x - h;                 // exact
  float m = trunchf(r); ms = hi16(r);
  float r2 = r - m;                // exact
  ls = hi16(r2);
}

// ---------------------------------------------------------------- W pre-split into fragment-direct layout
// dst layout: [p(3)][nt(4)][g16(8)][kc(16)][lane(64)][8] ushorts per mat.
// fragment (p,nt,g16,kc): lane l covers row nt*128+g16*16+(l&15), cols kc*32+(l>>4)*8 .. +8
__global__ __launch_bounds__(256) void wsplit(const float* __restrict__ Wq,
                                              const float* __restrict__ Wk,
                                              const float* __restrict__ Wv,
                                              unsigned short* __restrict__ dst,
                                              int matArg) {
  const int mat = (matArg >= 0) ? matArg : (int)blockIdx.y;
  const float* W = (mat == 0) ? Wq : (mat == 1) ? Wk : Wv;
  unsigned short* d = dst + ((matArg >= 0) ? 0 : (size_t)mat * WSPM);
  const int t = threadIdx.x;
  const int nt = blockIdx.x >> 3, g16 = blockIdx.x & 7;
  const int kc = t >> 4, lr = t & 15;
  const int n = nt*128 + g16*16 + lr;
  const float* src = W + (size_t)n*512 + kc*32;
  float xs[32];
#pragma unroll
  for (int i = 0; i < 8; ++i) {
    float4 v4 = ld4(src + 4*i);
    xs[4*i] = v4.x; xs[4*i+1] = v4.y; xs[4*i+2] = v4.z; xs[4*i+3] = v4.w;
  }
  unsigned short Hs[32], Ms[32], Ls[32];
#pragma unroll
  for (int e = 0; e < 32; ++e) tsplit(xs[e], Hs[e], Ms[e], Ls[e]);
#pragma unroll
  for (int p = 0; p < 3; ++p) {
    const unsigned short* sp = (p == 0) ? Hs : (p == 1) ? Ms : Ls;
    unsigned short* base = d + ((size_t)((p*4 + nt)*8 + g16)*16 + kc)*512;
#pragma unroll
    for (int lg = 0; lg < 4; ++lg) {
      union { bf16x8 v; unsigned short u[8]; } P;
#pragma unroll
      for (int e = 0; e < 8; ++e) P.u[e] = sp[lg*8 + e];
      *reinterpret_cast<bf16x8*>(base + (lr + 16*lg)*8) = P.v;
    }
  }
}

// ---------------------------------------------------------------- projection GEMM, split-bf16 MFMA
// A staged+split in LDS; W fragments read pre-split from global (L2-resident).
// grid (32 mtiles, 4 ntiles[, 3 mats]), 256 thr = 4 waves (2x2), wave tile 64x64.
__global__ __launch_bounds__(256) void proj_mfma2(
    const float* __restrict__ qa, const float* __restrict__ ka, const float* __restrict__ va,
    const unsigned short* __restrict__ wsp,
    const float* __restrict__ bq, const float* __restrict__ bk, const float* __restrict__ bv,
    float* __restrict__ qp, float* __restrict__ kp, float* __restrict__ vp,
    int matArg)
{
  __shared__ __align__(16) unsigned short a3[3][128][36];
  const int t = threadIdx.x;
  const int mat = (matArg >= 0) ? matArg : (int)blockIdx.z;
  const float* A    = (mat == 0) ? qa : (mat == 1) ? ka : va;
  const float* bias = (mat == 0) ? bq : (mat == 1) ? bk : bv;
  float* C          = (mat == 0) ? qp : (mat == 1) ? kp : vp;
  const unsigned short* wspm = wsp + ((matArg >= 0) ? 0 : (size_t)mat * WSPM);
  const int m0 = blockIdx.x * 128, nt = blockIdx.y;
  const int w = t >> 6, l = t & 63;
  const int wm = w >> 1, wn = w & 1;
  const int lr = l & 15, lg = l >> 4;
  const int srow = t >> 1, sc0 = (t & 1) * 16;

  f32x4 acc[4][4];
#pragma unroll
  for (int i = 0; i < 4; ++i)
#pragma unroll
    for (int j = 0; j < 4; ++j) acc[i][j] = (f32x4){0.f, 0.f, 0.f, 0.f};

  for (int kc = 0; kc < 16; ++kc) {
    __syncthreads();                       // prior chunk's af reads done
    // issue W fragment loads (coalesced 1KB each; latency hides under A staging)
    bf16x8 bw[3][4];
#pragma unroll
    for (int p = 0; p < 3; ++p)
#pragma unroll
      for (int ni = 0; ni < 4; ++ni)
        bw[p][ni] = *reinterpret_cast<const bf16x8*>(
            wspm + ((size_t)((p*4 + nt)*8 + wn*4 + ni)*16 + kc)*512 + l*8);
    {  // stage A tile rows m0+srow, 16 k-cols, trunc-split -> 3 planes
      const float* src = A + (size_t)(m0 + srow) * 512 + kc*32 + sc0;
      float xs[16];
#pragma unroll
      for (int i = 0; i < 4; ++i) {
        float4 v4 = ld4(src + 4*i);
        xs[4*i] = v4.x; xs[4*i+1] = v4.y; xs[4*i+2] = v4.z; xs[4*i+3] = v4.w;
      }
#pragma unroll
      for (int hh = 0; hh < 2; ++hh) {
        union { bf16x8 v; unsigned short u[8]; } H, M, L;
#pragma unroll
        for (int e = 0; e < 8; ++e) tsplit(xs[hh*8 + e], H.u[e], M.u[e], L.u[e]);
        *reinterpret_cast<bf16x8*>(&a3[0][srow][sc0 + 8*hh]) = H.v;
        *reinterpret_cast<bf16x8*>(&a3[1][srow][sc0 + 8*hh]) = M.v;
        *reinterpret_cast<bf16x8*>(&a3[2][srow][sc0 + 8*hh]) = L.v;
      }
    }
    __syncthreads();                       // planes ready

#pragma unroll
    for (int mi = 0; mi < 4; ++mi) {
      bf16x8 a0 = *reinterpret_cast<const bf16x8*>(&a3[0][wm*64 + mi*16 + lr][lg*8]);
      bf16x8 a1 = *reinterpret_cast<const bf16x8*>(&a3[1][wm*64 + mi*16 + lr][lg*8]);
      bf16x8 a2 = *reinterpret_cast<const bf16x8*>(&a3[2][wm*64 + mi*16 + lr][lg*8]);
#pragma unroll
      for (int ni = 0; ni < 4; ++ni) {
        acc[mi][ni] = __builtin_amdgcn_mfma_f32_16x16x32_bf16(a0, bw[0][ni], acc[mi][ni], 0, 0, 0); // hh
        acc[mi][ni] = __builtin_amdgcn_mfma_f32_16x16x32_bf16(a0, bw[1][ni], acc[mi][ni], 0, 0, 0); // hm
        acc[mi][ni] = __builtin_amdgcn_mfma_f32_16x16x32_bf16(a1, bw[0][ni], acc[mi][ni], 0, 0, 0); // mh
        acc[mi][ni] = __builtin_amdgcn_mfma_f32_16x16x32_bf16(a1, bw[1][ni], acc[mi][ni], 0, 0, 0); // mm
        acc[mi][ni] = __builtin_amdgcn_mfma_f32_16x16x32_bf16(a0, bw[2][ni], acc[mi][ni], 0, 0, 0); // hl
        acc[mi][ni] = __builtin_amdgcn_mfma_f32_16x16x32_bf16(a2, bw[0][ni], acc[mi][ni], 0, 0, 0); // lh
      }
    }
  }
  // epilogue: D row = m (lg*4+r), col = n (lr)
#pragma unroll
  for (int mi = 0; mi < 4; ++mi)
#pragma unroll
    for (int ni = 0; ni < 4; ++ni) {
      const int gn = nt*128 + wn*64 + ni*16 + lr;
      const float bv_ = bias[gn];
#pragma unroll
      for (int r = 0; r < 4; ++r) {
        const int gm = m0 + wm*64 + mi*16 + lg*4 + r;
        C[(size_t)gm * 512 + gn] = acc[mi][ni][r] + bv_;
      }
    }
}

// ---------------------------------------------------------------- Ksum[bh][j] = sum_s kp[b, idx[s], h*64+j]
__global__ __launch_bounds__(1024) void ksum_kernel(const float* __restrict__ kp,
                                                    const int* __restrict__ idx,
                                                    float* __restrict__ ksum) {
  __shared__ float part[16][64];
  const int bh = blockIdx.x;
  const int b = bh >> 3, h = bh & 7;
  const int t = threadIdx.x;
  const int sg = t >> 6, j = t & 63;
  const float* kbase = kp + (size_t)b*BHD + h*DH;
  float a = 0.f;
  for (int s = sg*128; s < sg*128 + 128; ++s)
    a += kbase[(size_t)idx[s]*512 + j];
  part[sg][j] = a;
  __syncthreads();
  if (t < 64) {
    float s = 0.f;
#pragma unroll
    for (int i = 0; i < 16; ++i) s += part[i][t];
    ksum[bh*64 + t] = s;
  }
}

// ---------------------------------------------------------------- Mp[ks][bh][q] = max over 1024 sampled keys of q.k
__global__ __launch_bounds__(256) void m_kernel(const float* __restrict__ qp,
                                                const float* __restrict__ kp,
                                                const int* __restrict__ idx,
                                                float* __restrict__ Mp) {
  __shared__ __align__(16) unsigned short k3[3][128][72];
  const int t = threadIdx.x;
  const int bid = blockIdx.x;
  const int bh = bid >> 4, qt = (bid >> 1) & 7, ks = bid & 1;
  const int b = bh >> 3, h = bh & 7;
  const int w = t >> 6, l = t & 63;
  const int lr = l & 15;
  const int lg = l >> 4;

  bf16x8 qf[4][2][3];
  {
    const float* qbase = qp + (size_t)b*BHD + (size_t)h*QHS + (size_t)(qt*256 + w*64 + lr) * 64 + lg*8;
#pragma unroll
    for (int mi = 0; mi < 4; ++mi)
#pragma unroll
      for (int c = 0; c < 2; ++c) {
        const float* src = qbase + mi*16*64 + c*32;
        float4 x0 = ld4(src), x1 = ld4(src + 4);
        float xs[8] = {x0.x, x0.y, x0.z, x0.w, x1.x, x1.y, x1.z, x1.w};
        union { bf16x8 v; unsigned short u[8]; } H, M, L;
#pragma unroll
        for (int e = 0; e < 8; ++e) tsplit(xs[e], H.u[e], M.u[e], L.u[e]);
        qf[mi][c][0] = H.v; qf[mi][c][1] = M.v; qf[mi][c][2] = L.v;
      }
  }

  const float* kbase = kp + (size_t)b*BHD + h*DH;
  const int ib = ks * 1024;
  const int srow = t >> 1, sh = (t & 1) * 32;

  float4 vst[8];
  {
    const int kr = idx[ib + srow];
    const float* src = kbase + (size_t)kr * 512 + sh;
#pragma unroll
    for (int i = 0; i < 8; ++i) vst[i] = ld4(src + 4*i);
  }

  float mx[4][4];
#pragma unroll
  for (int mi = 0; mi < 4; ++mi)
#pragma unroll
    for (int r = 0; r < 4; ++r) mx[mi][r] = -INFINITY;

  for (int tl = 0; tl < 8; ++tl) {
    __syncthreads();
    {
#pragma unroll
      for (int e2 = 0; e2 < 4; ++e2) {
        union { bf16x8 v; unsigned short u[8]; } H, M, L;
        float xs[8] = {vst[2*e2].x, vst[2*e2].y, vst[2*e2].z, vst[2*e2].w,
                       vst[2*e2+1].x, vst[2*e2+1].y, vst[2*e2+1].z, vst[2*e2+1].w};
#pragma unroll
        for (int e = 0; e < 8; ++e) tsplit(xs[e], H.u[e], M.u[e], L.u[e]);
        *reinterpret_cast<bf16x8*>(&k3[0][srow][sh + 8*e2]) = H.v;
        *reinterpret_cast<bf16x8*>(&k3[1][srow][sh + 8*e2]) = M.v;
        *reinterpret_cast<bf16x8*>(&k3[2][srow][sh + 8*e2]) = L.v;
      }
    }
    if (tl < 7) {
      const int kr = idx[ib + (tl+1)*128 + srow];
      const float* src = kbase + (size_t)kr * 512 + sh;
#pragma unroll
      for (int i = 0; i < 8; ++i) vst[i] = ld4(src + 4*i);
    }
    __syncthreads();

    for (int n2 = 0; n2 < 4; ++n2) {
      bf16x8 bf[2][3][2];
#pragma unroll
      for (int ns = 0; ns < 2; ++ns)
#pragma unroll
        for (int p = 0; p < 3; ++p)
#pragma unroll
          for (int c = 0; c < 2; ++c)
            bf[ns][p][c] = *reinterpret_cast<const bf16x8*>(&k3[p][n2*32 + ns*16 + lr][c*32 + lg*8]);
#pragma unroll
      for (int mi = 0; mi < 4; ++mi)
#pragma unroll
        for (int ns = 0; ns < 2; ++ns) {
          f32x4 acc = {0.f, 0.f, 0.f, 0.f};
#pragma unroll
          for (int c = 0; c < 2; ++c) acc = __builtin_amdgcn_mfma_f32_16x16x32_bf16(qf[mi][c][0], bf[ns][0][c], acc, 0, 0, 0); // hh
#pragma unroll
          for (int c = 0; c < 2; ++c) acc = __builtin_amdgcn_mfma_f32_16x16x32_bf16(qf[mi][c][0], bf[ns][1][c], acc, 0, 0, 0); // hm
#pragma unroll
          for (int c = 0; c < 2; ++c) acc = __builtin_amdgcn_mfma_f32_16x16x32_bf16(qf[mi][c][1], bf[ns][0][c], acc, 0, 0, 0); // mh
#pragma unroll
          for (int c = 0; c < 2; ++c) acc = __builtin_amdgcn_mfma_f32_16x16x32_bf16(qf[mi][c][1], bf[ns][1][c], acc, 0, 0, 0); // mm
#pragma unroll
          for (int c = 0; c < 2; ++c) acc = __builtin_amdgcn_mfma_f32_16x16x32_bf16(qf[mi][c][0], bf[ns][2][c], acc, 0, 0, 0); // hl
#pragma unroll
          for (int c = 0; c < 2; ++c) acc = __builtin_amdgcn_mfma_f32_16x16x32_bf16(qf[mi][c][2], bf[ns][0][c], acc, 0, 0, 0); // lh
#pragma unroll
          for (int r = 0; r < 4; ++r) mx[mi][r] = fmaxf(mx[mi][r], acc[r]);
        }
    }
  }

#pragma unroll
  for (int mi = 0; mi < 4; ++mi)
#pragma unroll
    for (int r = 0; r < 4; ++r) {
      float v = mx[mi][r];
      v = fmaxf(v, __shfl_xor(v, 1));
      v = fmaxf(v, __shfl_xor(v, 2));
      v = fmaxf(v, __shfl_xor(v, 4));
      v = fmaxf(v, __shfl_xor(v, 8));
      if (lr == 0)
        Mp[ks*32768 + bh*2048 + qt*256 + w*64 + mi*16 + lg*4 + r] = v;
    }
}

// ---------------------------------------------------------------- fused M-finalize + top-40 via radix-select
__global__ __launch_bounds__(256) void topk_kernel(const float* __restrict__ qp,
                                                   const float* __restrict__ ksum,
                                                   const float* __restrict__ Mp,
                                                   int* __restrict__ Mtop) {
  __shared__ float ks_s[64];
  __shared__ unsigned hist[256];
  __shared__ int wsum[4];
  __shared__ unsigned bitmap[64];
  __shared__ unsigned long long comb[NU];
  __shared__ int s_sel, s_rem, s_cnt;
  const int bh = blockIdx.x;
  const int b = bh >> 3, h = bh & 7;
  const int t = threadIdx.x;
  if (t < 64) ks_s[t] = ksum[bh*64 + t];
  __syncthreads();

  unsigned mykey[8];
#pragma unroll
  for (int c = 0; c < 8; ++c) {
    const int qi = c * 256 + t;
    const float* qrow = qp + (size_t)b*BHD + (size_t)h*QHS + (size_t)qi * 64;
    float dot = 0.f;
#pragma unroll
    for (int cc = 0; cc < 16; ++cc) {
      float4 q4 = ld4(qrow + 4 * cc);
      dot += q4.x * ks_s[4*cc + 0];
      dot += q4.y * ks_s[4*cc + 1];
      dot += q4.z * ks_s[4*cc + 2];
      dot += q4.w * ks_s[4*cc + 3];
    }
    const float m = fmaxf(Mp[bh*2048 + qi], Mp[32768 + bh*2048 + qi]) - dot * (1.0f/2048.0f);
    const unsigned u = __float_as_uint(m);
    mykey[c] = (u >> 31) ? ~u : (u | 0x80000000u);
  }

  unsigned prefMask = 0u, prefVal = 0u;
  int rem = NU;
  for (int shift = 24; shift >= 0; shift -= 8) {
    hist[t] = 0;
    __syncthreads();
#pragma unroll
    for (int c = 0; c < 8; ++c) {
      const unsigned key = mykey[c];
      if ((key & prefMask) == prefVal)
        atomicAdd(&hist[(key >> shift) & 255], 1u);
    }
    __syncthreads();
    const int binc = (int)hist[t];
    int inc = binc;
#pragma unroll
    for (int off = 1; off < 64; off <<= 1) {
      const int nb = __shfl_up(inc, off);
      if ((t & 63) >= off) inc += nb;
    }
    if ((t & 63) == 63) wsum[t >> 6] = inc;
    __syncthreads();
    int wadd = 0;
    for (int w2 = 0; w2 < (t >> 6); ++w2) wadd += wsum[w2];
    const int incl = inc + wadd;
    const int excl = incl - binc;
    if (excl < rem && rem <= incl) { s_sel = t; s_rem = rem - excl; }
    __syncthreads();
    prefVal |= ((unsigned)s_sel) << shift;
    prefMask |= 0xFFu << shift;
    rem = s_rem;
    __syncthreads();
  }
  const unsigned T = prefVal;

  if (t < 64) bitmap[t] = 0;
  if (t == 0) s_cnt = 0;
  __syncthreads();
#pragma unroll
  for (int c = 0; c < 8; ++c) {
    const unsigned key = mykey[c];
    const int qi = c * 256 + t;
    if (key < T) {
      const int pos = atomicAdd(&s_cnt, 1);
      comb[pos] = ((unsigned long long)key << 11) | (unsigned)qi;
    } else if (key == T) {
      atomicOr(&bitmap[qi >> 5], 1u << (qi & 31));
    }
  }
  __syncthreads();
  if (t == 0) {
    int need = rem, cpos = s_cnt;
    for (int wd = 0; wd < 64 && need > 0; ++wd) {
      unsigned bits = bitmap[wd];
      while (bits && need > 0) {
        const int bit = __ffs(bits) - 1;
        bits &= bits - 1;
        comb[cpos++] = ((unsigned long long)T << 11) | (unsigned)(wd*32 + bit);
        --need;
      }
    }
  }
  __syncthreads();

  if (t < 64) {
    const unsigned long long mine = (t < NU) ? comb[t] : ~0ULL;
    int rank = 0;
#pragma unroll
    for (int step = 1; step < 64; ++step) {
      const unsigned long long other = __shfl(mine, (t + step) & 63);
      rank += (other < mine) ? 1 : 0;
    }
    if (t < NU) Mtop[bh*NU + rank] = (int)(mine & 0x7FFu);
  }
}

// ---------------------------------------------------------------- flash partials over 128-key slabs
__global__ __launch_bounds__(256) void flash_partial(const float* __restrict__ qp,
                                                     const float* __restrict__ kp,
                                                     const float* __restrict__ vp,
                                                     const int* __restrict__ Mtop,
                                                     float* __restrict__ pm,
                                                     float* __restrict__ pl,
                                                     float* __restrict__ pacc) {
  __shared__ float qr[NU][65];
  __shared__ float kv[64][65];
  __shared__ float sl[NU][65];
  __shared__ float ms[NU], ls[NU], fs[NU];
  const int bid = blockIdx.x;
  const int bh = bid >> 4, kt = bid & 15;
  const int b = bh >> 3, h = bh & 7;
  const int t = threadIdx.x;
  const int g = t >> 6, j = t & 63;
  const int r4 = t >> 2, sub = t & 3;

  {
    const float* qbase = qp + (size_t)b*BHD + (size_t)h*QHS;
#pragma unroll
    for (int r = 0; r < 10; ++r) {
      const int q = g*10 + r;
      qr[q][j] = qbase[(size_t)Mtop[bh*NU + q]*64 + j];
    }
  }
  if (t < NU) { ms[t] = -INFINITY; ls[t] = 0.f; }
  float acc[10];
#pragma unroll
  for (int r = 0; r < 10; ++r) acc[r] = 0.f;

  const float* kbase = kp + (size_t)b*BHD + h*DH;
  const float* vbase = vp + (size_t)b*BHD + h*DH;
  const int srow = t >> 2, scb = (t & 3)*16;

  for (int st = 0; st < 2; ++st) {
    const int kb = kt*128 + st*64;
    __syncthreads();
    {
      const float* src = kbase + (size_t)(kb + srow)*512 + scb;
#pragma unroll
      for (int i = 0; i < 4; ++i) {
        float4 v = ld4(src + 4*i);
        kv[srow][scb + 4*i + 0] = v.x;
        kv[srow][scb + 4*i + 1] = v.y;
        kv[srow][scb + 4*i + 2] = v.z;
        kv[srow][scb + 4*i + 3] = v.w;
      }
    }
    __syncthreads();
    {
      float sv[10];
#pragma unroll
      for (int r = 0; r < 10; ++r) {
        const int q = g*10 + r;
        float s = 0.f;
#pragma unroll 8
        for (int jj = 0; jj < 64; ++jj) s += qr[q][jj]*kv[j][jj];
        sv[r] = s * 0.125f;
      }
#pragma unroll
      for (int r = 0; r < 10; ++r) sl[g*10 + r][j] = sv[r];
    }
    __syncthreads();
    float4 vst[4];
    {
      const float* src = vbase + (size_t)(kb + srow)*512 + scb;
#pragma unroll
      for (int i = 0; i < 4; ++i) vst[i] = ld4(src + 4*i);
    }
    if (r4 < NU) {
      float tm = -INFINITY;
#pragma unroll
      for (int c = 0; c < 16; ++c) tm = fmaxf(tm, sl[r4][sub*16 + c]);
      tm = fmaxf(tm, __shfl_xor(tm, 1));
      tm = fmaxf(tm, __shfl_xor(tm, 2));
      const float nm = fmaxf(ms[r4], tm);
      if (sub == 0) { fs[r4] = expf(ms[r4] - nm); ms[r4] = nm; }
    }
    __syncthreads();
    {
#pragma unroll
      for (int r = 0; r < 10; ++r) {
        const int q = g*10 + r;
        acc[r] *= fs[q];
        sl[q][j] = expf(sl[q][j] - ms[q]);
      }
#pragma unroll
      for (int i = 0; i < 4; ++i) {
        kv[srow][scb + 4*i + 0] = vst[i].x;
        kv[srow][scb + 4*i + 1] = vst[i].y;
        kv[srow][scb + 4*i + 2] = vst[i].z;
        kv[srow][scb + 4*i + 3] = vst[i].w;
      }
    }
    __syncthreads();
    if (r4 < NU) {
      float s = 0.f;
#pragma unroll
      for (int c = 0; c < 16; ++c) s += sl[r4][sub*16 + c];
      s += __shfl_xor(s, 1);
      s += __shfl_xor(s, 2);
      if (sub == 0) ls[r4] = ls[r4]*fs[r4] + s;
    }
    {
#pragma unroll 4
      for (int kk = 0; kk < 64; ++kk) {
        const float vv = kv[kk][j];
#pragma unroll
        for (int r = 0; r < 10; ++r) acc[r] += sl[g*10 + r][kk]*vv;
      }
    }
  }
  __syncthreads();
  const size_t base = (size_t)(bh*16 + kt)*NU;
  if (t < NU) { pm[base + t] = ms[t]; pl[base + t] = ls[t]; }
#pragma unroll
  for (int r = 0; r < 10; ++r)
    pacc[(base + g*10 + r)*64 + j] = acc[r];
}

// ---------------------------------------------------------------- combine 16 partials, write outc (B,40,512)
__global__ __launch_bounds__(256) void flash_combine(const float* __restrict__ pm,
                                                     const float* __restrict__ pl,
                                                     const float* __restrict__ pacc,
                                                     float* __restrict__ outc) {
  const int t = threadIdx.x;
  const int qg = t >> 6, j = t & 63;
  const int bh = blockIdx.x / 10;
  const int q  = (blockIdx.x % 10)*4 + qg;
  const int b = bh >> 3, h = bh & 7;
  float m = -INFINITY;
#pragma unroll
  for (int kt = 0; kt < 16; ++kt) m = fmaxf(m, pm[(size_t)(bh*16 + kt)*NU + q]);
  float Lsum = 0.f, num = 0.f;
#pragma unroll
  for (int kt = 0; kt < 16; ++kt) {
    const size_t base = (size_t)(bh*16 + kt)*NU;
    const float w = expf(pm[base + q] - m);
    Lsum += w * pl[base + q];
    num  += w * pacc[(base + q)*64 + j];
  }
  outc[(size_t)(b*NU + q)*512 + h*64 + j] = num / Lsum;
}

// ---------------------------------------------------------------- Wo GEMM, split-k x4
__global__ __launch_bounds__(256) void wo_gemm(const float* __restrict__ outc,
                                               const float* __restrict__ Wo,
                                               float* __restrict__ pwo) {
  __shared__ __align__(16) float a_t[80][68];
  __shared__ __align__(16) float w_t[64][68];
  const int t = threadIdx.x;
  const int ty = t >> 4, tx = t & 15;
  const int nt = blockIdx.x, ks = blockIdx.y;
  float acc[5][4];
#pragma unroll
  for (int i = 0; i < 5; ++i)
#pragma unroll
    for (int j = 0; j < 4; ++j) acc[i][j] = 0.f;

  for (int c = 0; c < 2; ++c) {
    const int kb = ks*128 + c*64;
    __syncthreads();
#pragma unroll
    for (int i = 0; i < 20; ++i) {
      const int fi = t + 256*i;
      const int row = fi >> 6, col = fi & 63;
      a_t[row][col] = outc[(size_t)row*512 + kb + col];
    }
#pragma unroll
    for (int i = 0; i < 16; ++i) {
      const int fi = t + 256*i;
      const int row = fi >> 6, col = fi & 63;
      w_t[row][col] = Wo[(size_t)(nt*64 + row)*512 + kb + col];
    }
    __syncthreads();
    for (int gq = 0; gq < 16; ++gq) {
      float4 av[5], wv[4];
#pragma unroll
      for (int i = 0; i < 5; ++i) av[i] = *reinterpret_cast<const float4*>(&a_t[ty + 16*i][4*gq]);
#pragma unroll
      for (int j = 0; j < 4; ++j) wv[j] = *reinterpret_cast<const float4*>(&w_t[tx + 16*j][4*gq]);
#pragma unroll
      for (int i = 0; i < 5; ++i)
#pragma unroll
        for (int j = 0; j < 4; ++j) {
          acc[i][j] += av[i].x * wv[j].x;
          acc[i][j] += av[i].y * wv[j].y;
          acc[i][j] += av[i].z * wv[j].z;
          acc[i][j] += av[i].w * wv[j].w;
        }
    }
  }
#pragma unroll
  for (int i = 0; i < 5; ++i)
#pragma unroll
    for (int j = 0; j < 4; ++j)
      pwo[ks*40960 + (size_t)(ty + 16*i)*512 + nt*64 + tx + 16*j] = acc[i][j];
}

__global__ __launch_bounds__(256) void wo_combine(const float* __restrict__ pwo,
                                                  const float* __restrict__ bo,
                                                  float* __restrict__ out) {
  const int gi = blockIdx.x*256 + threadIdx.x;
  const float4* p = reinterpret_cast<const float4*>(pwo);
  const float4 a = p[gi], b4 = p[10240 + gi], c4 = p[20480 + gi], d4 = p[30720 + gi];
  const float4 bb = ld4(bo + 4*(gi & 127));
  float4 o;
  o.x = a.x + b4.x + c4.x + d4.x + bb.x;
  o.y = a.y + b4.y + c4.y + d4.y + bb.y;
  o.z = a.z + b4.z + c4.z + d4.z + bb.z;
  o.w = a.w + b4.w + c4.w + d4.w + bb.w;
  reinterpret_cast<float4*>(out)[gi] = o;
}

// ----------------------------------------------------------------
extern "C" void kernel_launch(void* const* d_in, const int* in_sizes, int n_in,
                              void* d_out, int out_size, void* d_ws, size_t ws_size,
                              hipStream_t stream) {
  const float* q  = (const float*)d_in[0];
  const float* k  = (const float*)d_in[1];
  const float* v  = (const float*)d_in[2];
  const float* Wq = (const float*)d_in[3];
  const float* bq = (const float*)d_in[4];
  const float* Wk = (const float*)d_in[5];
  const float* bk = (const float*)d_in[6];
  const float* Wv = (const float*)d_in[7];
  const float* bv = (const float*)d_in[8];
  const float* Wo = (const float*)d_in[9];
  const float* bo = (const float*)d_in[10];
  const int*  idx = (const int*)d_in[11];

  float* ws   = (float*)d_ws;
  float* qp   = ws;                        // 2,097,152
  float* kp   = ws + 2097152;              // 2,097,152
  float* vp   = ws + 4194304;              // 2,097,152
  float* ksum = ws + 6291456;              // 1,024
  int*   Mtop = (int*)(ws + 6292480);      // 640
  float* pm   = ws + 6293120;              // 10,240
  float* pl   = ws + 6303360;              // 10,240
  float* pacc = ws + 6313600;              // 655,360
  float* outc = ws + 6968960;              // 40,960  (end 7,009,920)
  // time-disjoint aliases:
  float* Mp   = pm;                        // dead before flash_partial
  float* pwo  = pm;                        // written after flash_combine reads pm/pl/pacc
  // W-split planes live only during wsplit+proj (before ksum etc. are written):
  unsigned short* wsp = (unsigned short*)(ws + 6291456);

  const dim3 blk(256);
  const bool bigws = (ws_size >= (size_t)7471104 * 4);   // 3-mat W-split extends ws to 29.9 MB
  if (bigws) {
    wsplit<<<dim3(32, 3), blk, 0, stream>>>(Wq, Wk, Wv, wsp, -1);
    proj_mfma2<<<dim3(32, 4, 3), blk, 0, stream>>>(q, k, v, wsp, bq, bk, bv, qp, kp, vp, -1);
  } else {
    for (int m = 0; m < 3; ++m) {        // sequential per-mat fallback (identical numerics)
      wsplit<<<dim3(32, 1), blk, 0, stream>>>(Wq, Wk, Wv, wsp, m);
      proj_mfma2<<<dim3(32, 4, 1), blk, 0, stream>>>(q, k, v, wsp, bq, bk, bv, qp, kp, vp, m);
    }
  }
  ksum_kernel<<<dim3(16), dim3(1024), 0, stream>>>(kp, idx, ksum);
  m_kernel<<<dim3(256), blk, 0, stream>>>(qp, kp, idx, Mp);
  topk_kernel<<<dim3(16), blk, 0, stream>>>(qp, ksum, Mp, Mtop);
  flash_partial<<<dim3(256), blk, 0, stream>>>(qp, kp, vp, Mtop, pm, pl, pacc);
  flash_combine<<<dim3(160), blk, 0, stream>>>(pm, pl, pacc, outc);
  wo_gemm<<<dim3(8, 4), blk, 0, stream>>>(outc, Wo, pwo);
  wo_combine<<<dim3(40), blk, 0, stream>>>(pwo, bo, (float*)d_out);
}

// Round 7
// 190.245 us; speedup vs baseline: 3.1346x; 1.0311x over previous
//
#include <hip/hip_runtime.h>
#include <math.h>

#define B_ 2
#define L_ 2048
#define D_ 512
#define H_ 8
#define DH 64
#define NS 2048   // U_part (sampled keys)
#define NU 40     // u (selected queries)
#define BHD (L_*D_)        // per-batch stride of qp/kp/vp
#define QHS (L_*DH)        // per-head stride inside qh view
#define WSPM 786432        // ushorts per mat in the W-split buffer

typedef __attribute__((ext_vector_type(8))) short bf16x8;
typedef __attribute__((ext_vector_type(4))) float f32x4;

__device__ inline float4 ld4(const float* p) { return *reinterpret_cast<const float4*>(p); }

// truncation split: x = h + m + r, all bf16-representable (exact truncations).
// 6-product MFMA (hh,hm,mh,mm,hl,lh) == fp32-class dot.
__device__ inline unsigned short hi16(float x) { return (unsigned short)(__float_as_uint(x) >> 16); }
__device__ inline float trunchf(float x) { return __uint_as_float(__float_as_uint(x) & 0xFFFF0000u); }
__device__ inline void tsplit(float x, unsigned short& hs, unsigned short& ms, unsigned short& ls) {
  float h = trunchf(x); hs = hi16(x);
  float r = x - h;                 // exact
  float m = trunchf(r); ms = hi16(r);
  float r2 = r - m;                // exact
  ls = hi16(r2);
}

// ---------------------------------------------------------------- W pre-split into fragment-direct layout
// dst layout: [p(3)][nt(4)][g16(8)][kc(16)][lane(64)][8] ushorts per mat.
__global__ __launch_bounds__(256) void wsplit(const float* __restrict__ Wq,
                                              const float* __restrict__ Wk,
                                              const float* __restrict__ Wv,
                                              unsigned short* __restrict__ dst,
                                              int matArg) {
  const int mat = (matArg >= 0) ? matArg : (int)blockIdx.y;
  const float* W = (mat == 0) ? Wq : (mat == 1) ? Wk : Wv;
  unsigned short* d = dst + ((matArg >= 0) ? 0 : (size_t)mat * WSPM);
  const int t = threadIdx.x;
  const int nt = blockIdx.x >> 3, g16 = blockIdx.x & 7;
  const int kc = t >> 4, lr = t & 15;
  const int n = nt*128 + g16*16 + lr;
  const float* src = W + (size_t)n*512 + kc*32;
  float xs[32];
#pragma unroll
  for (int i = 0; i < 8; ++i) {
    float4 v4 = ld4(src + 4*i);
    xs[4*i] = v4.x; xs[4*i+1] = v4.y; xs[4*i+2] = v4.z; xs[4*i+3] = v4.w;
  }
  unsigned short Hs[32], Ms[32], Ls[32];
#pragma unroll
  for (int e = 0; e < 32; ++e) tsplit(xs[e], Hs[e], Ms[e], Ls[e]);
#pragma unroll
  for (int p = 0; p < 3; ++p) {
    const unsigned short* sp = (p == 0) ? Hs : (p == 1) ? Ms : Ls;
    unsigned short* base = d + ((size_t)((p*4 + nt)*8 + g16)*16 + kc)*512;
#pragma unroll
    for (int lg = 0; lg < 4; ++lg) {
      union { bf16x8 v; unsigned short u[8]; } P;
#pragma unroll
      for (int e = 0; e < 8; ++e) P.u[e] = sp[lg*8 + e];
      *reinterpret_cast<bf16x8*>(base + (lr + 16*lg)*8) = P.v;
    }
  }
}

// ---------------------------------------------------------------- projection GEMM, split-bf16 MFMA
__global__ __launch_bounds__(256) void proj_mfma2(
    const float* __restrict__ qa, const float* __restrict__ ka, const float* __restrict__ va,
    const unsigned short* __restrict__ wsp,
    const float* __restrict__ bq, const float* __restrict__ bk, const float* __restrict__ bv,
    float* __restrict__ qp, float* __restrict__ kp, float* __restrict__ vp,
    int matArg)
{
  __shared__ __align__(16) unsigned short a3[3][128][36];
  const int t = threadIdx.x;
  const int mat = (matArg >= 0) ? matArg : (int)blockIdx.z;
  const float* A    = (mat == 0) ? qa : (mat == 1) ? ka : va;
  const float* bias = (mat == 0) ? bq : (mat == 1) ? bk : bv;
  float* C          = (mat == 0) ? qp : (mat == 1) ? kp : vp;
  const unsigned short* wspm = wsp + ((matArg >= 0) ? 0 : (size_t)mat * WSPM);
  const int m0 = blockIdx.x * 128, nt = blockIdx.y;
  const int w = t >> 6, l = t & 63;
  const int wm = w >> 1, wn = w & 1;
  const int lr = l & 15, lg = l >> 4;
  const int srow = t >> 1, sc0 = (t & 1) * 16;

  f32x4 acc[4][4];
#pragma unroll
  for (int i = 0; i < 4; ++i)
#pragma unroll
    for (int j = 0; j < 4; ++j) acc[i][j] = (f32x4){0.f, 0.f, 0.f, 0.f};

  for (int kc = 0; kc < 16; ++kc) {
    __syncthreads();
    bf16x8 bw[3][4];
#pragma unroll
    for (int p = 0; p < 3; ++p)
#pragma unroll
      for (int ni = 0; ni < 4; ++ni)
        bw[p][ni] = *reinterpret_cast<const bf16x8*>(
            wspm + ((size_t)((p*4 + nt)*8 + wn*4 + ni)*16 + kc)*512 + l*8);
    {
      const float* src = A + (size_t)(m0 + srow) * 512 + kc*32 + sc0;
      float xs[16];
#pragma unroll
      for (int i = 0; i < 4; ++i) {
        float4 v4 = ld4(src + 4*i);
        xs[4*i] = v4.x; xs[4*i+1] = v4.y; xs[4*i+2] = v4.z; xs[4*i+3] = v4.w;
      }
#pragma unroll
      for (int hh = 0; hh < 2; ++hh) {
        union { bf16x8 v; unsigned short u[8]; } H, M, L;
#pragma unroll
        for (int e = 0; e < 8; ++e) tsplit(xs[hh*8 + e], H.u[e], M.u[e], L.u[e]);
        *reinterpret_cast<bf16x8*>(&a3[0][srow][sc0 + 8*hh]) = H.v;
        *reinterpret_cast<bf16x8*>(&a3[1][srow][sc0 + 8*hh]) = M.v;
        *reinterpret_cast<bf16x8*>(&a3[2][srow][sc0 + 8*hh]) = L.v;
      }
    }
    __syncthreads();

#pragma unroll
    for (int mi = 0; mi < 4; ++mi) {
      bf16x8 a0 = *reinterpret_cast<const bf16x8*>(&a3[0][wm*64 + mi*16 + lr][lg*8]);
      bf16x8 a1 = *reinterpret_cast<const bf16x8*>(&a3[1][wm*64 + mi*16 + lr][lg*8]);
      bf16x8 a2 = *reinterpret_cast<const bf16x8*>(&a3[2][wm*64 + mi*16 + lr][lg*8]);
#pragma unroll
      for (int ni = 0; ni < 4; ++ni) {
        acc[mi][ni] = __builtin_amdgcn_mfma_f32_16x16x32_bf16(a0, bw[0][ni], acc[mi][ni], 0, 0, 0); // hh
        acc[mi][ni] = __builtin_amdgcn_mfma_f32_16x16x32_bf16(a0, bw[1][ni], acc[mi][ni], 0, 0, 0); // hm
        acc[mi][ni] = __builtin_amdgcn_mfma_f32_16x16x32_bf16(a1, bw[0][ni], acc[mi][ni], 0, 0, 0); // mh
        acc[mi][ni] = __builtin_amdgcn_mfma_f32_16x16x32_bf16(a1, bw[1][ni], acc[mi][ni], 0, 0, 0); // mm
        acc[mi][ni] = __builtin_amdgcn_mfma_f32_16x16x32_bf16(a0, bw[2][ni], acc[mi][ni], 0, 0, 0); // hl
        acc[mi][ni] = __builtin_amdgcn_mfma_f32_16x16x32_bf16(a2, bw[0][ni], acc[mi][ni], 0, 0, 0); // lh
      }
    }
  }
#pragma unroll
  for (int mi = 0; mi < 4; ++mi)
#pragma unroll
    for (int ni = 0; ni < 4; ++ni) {
      const int gn = nt*128 + wn*64 + ni*16 + lr;
      const float bv_ = bias[gn];
#pragma unroll
      for (int r = 0; r < 4; ++r) {
        const int gm = m0 + wm*64 + mi*16 + lg*4 + r;
        C[(size_t)gm * 512 + gn] = acc[mi][ni][r] + bv_;
      }
    }
}

// ---------------------------------------------------------------- Ksum[bh][j] = sum_s kp[b, idx[s], h*64+j]
__global__ __launch_bounds__(1024) void ksum_kernel(const float* __restrict__ kp,
                                                    const int* __restrict__ idx,
                                                    float* __restrict__ ksum) {
  __shared__ float part[16][64];
  const int bh = blockIdx.x;
  const int b = bh >> 3, h = bh & 7;
  const int t = threadIdx.x;
  const int sg = t >> 6, j = t & 63;
  const float* kbase = kp + (size_t)b*BHD + h*DH;
  float a = 0.f;
  for (int s = sg*128; s < sg*128 + 128; ++s)
    a += kbase[(size_t)idx[s]*512 + j];
  part[sg][j] = a;
  __syncthreads();
  if (t < 64) {
    float s = 0.f;
#pragma unroll
    for (int i = 0; i < 16; ++i) s += part[i][t];
    ksum[bh*64 + t] = s;
  }
}

// ---------------------------------------------------------------- Mp[ks][bh][q] = max over 512 sampled keys of q.k
// grid 512: bh=bid>>5, qt=(bid>>2)&7 (256-q tiles), ks=bid&3 (512-key split) -> 2 blocks/CU.
__global__ __launch_bounds__(256, 2) void m_kernel(const float* __restrict__ qp,
                                                   const float* __restrict__ kp,
                                                   const int* __restrict__ idx,
                                                   float* __restrict__ Mp) {
  __shared__ __align__(16) unsigned short k3[3][128][72];
  const int t = threadIdx.x;
  const int bid = blockIdx.x;
  const int bh = bid >> 5, qt = (bid >> 2) & 7, ks = bid & 3;
  const int b = bh >> 3, h = bh & 7;
  const int w = t >> 6, l = t & 63;
  const int lr = l & 15;
  const int lg = l >> 4;

  bf16x8 qf[4][2][3];
  {
    const float* qbase = qp + (size_t)b*BHD + (size_t)h*QHS + (size_t)(qt*256 + w*64 + lr) * 64 + lg*8;
#pragma unroll
    for (int mi = 0; mi < 4; ++mi)
#pragma unroll
      for (int c = 0; c < 2; ++c) {
        const float* src = qbase + mi*16*64 + c*32;
        float4 x0 = ld4(src), x1 = ld4(src + 4);
        float xs[8] = {x0.x, x0.y, x0.z, x0.w, x1.x, x1.y, x1.z, x1.w};
        union { bf16x8 v; unsigned short u[8]; } H, M, L;
#pragma unroll
        for (int e = 0; e < 8; ++e) tsplit(xs[e], H.u[e], M.u[e], L.u[e]);
        qf[mi][c][0] = H.v; qf[mi][c][1] = M.v; qf[mi][c][2] = L.v;
      }
  }

  const float* kbase = kp + (size_t)b*BHD + h*DH;
  const int ib = ks * 512;
  const int srow = t >> 1, sh = (t & 1) * 32;

  float4 vst[8];
  {
    const int kr = idx[ib + srow];
    const float* src = kbase + (size_t)kr * 512 + sh;
#pragma unroll
    for (int i = 0; i < 8; ++i) vst[i] = ld4(src + 4*i);
  }

  float mx[4][4];
#pragma unroll
  for (int mi = 0; mi < 4; ++mi)
#pragma unroll
    for (int r = 0; r < 4; ++r) mx[mi][r] = -INFINITY;

  for (int tl = 0; tl < 4; ++tl) {
    __syncthreads();
    {
#pragma unroll
      for (int e2 = 0; e2 < 4; ++e2) {
        union { bf16x8 v; unsigned short u[8]; } H, M, L;
        float xs[8] = {vst[2*e2].x, vst[2*e2].y, vst[2*e2].z, vst[2*e2].w,
                       vst[2*e2+1].x, vst[2*e2+1].y, vst[2*e2+1].z, vst[2*e2+1].w};
#pragma unroll
        for (int e = 0; e < 8; ++e) tsplit(xs[e], H.u[e], M.u[e], L.u[e]);
        *reinterpret_cast<bf16x8*>(&k3[0][srow][sh + 8*e2]) = H.v;
        *reinterpret_cast<bf16x8*>(&k3[1][srow][sh + 8*e2]) = M.v;
        *reinterpret_cast<bf16x8*>(&k3[2][srow][sh + 8*e2]) = L.v;
      }
    }
    if (tl < 3) {
      const int kr = idx[ib + (tl+1)*128 + srow];
      const float* src = kbase + (size_t)kr * 512 + sh;
#pragma unroll
      for (int i = 0; i < 8; ++i) vst[i] = ld4(src + 4*i);
    }
    __syncthreads();

    for (int n2 = 0; n2 < 4; ++n2) {
      bf16x8 bf[2][3][2];
#pragma unroll
      for (int ns = 0; ns < 2; ++ns)
#pragma unroll
        for (int p = 0; p < 3; ++p)
#pragma unroll
          for (int c = 0; c < 2; ++c)
            bf[ns][p][c] = *reinterpret_cast<const bf16x8*>(&k3[p][n2*32 + ns*16 + lr][c*32 + lg*8]);
      __builtin_amdgcn_s_setprio(1);
#pragma unroll
      for (int mi = 0; mi < 4; ++mi)
#pragma unroll
        for (int ns = 0; ns < 2; ++ns) {
          f32x4 acc = {0.f, 0.f, 0.f, 0.f};
#pragma unroll
          for (int c = 0; c < 2; ++c) acc = __builtin_amdgcn_mfma_f32_16x16x32_bf16(qf[mi][c][0], bf[ns][0][c], acc, 0, 0, 0); // hh
#pragma unroll
          for (int c = 0; c < 2; ++c) acc = __builtin_amdgcn_mfma_f32_16x16x32_bf16(qf[mi][c][0], bf[ns][1][c], acc, 0, 0, 0); // hm
#pragma unroll
          for (int c = 0; c < 2; ++c) acc = __builtin_amdgcn_mfma_f32_16x16x32_bf16(qf[mi][c][1], bf[ns][0][c], acc, 0, 0, 0); // mh
#pragma unroll
          for (int c = 0; c < 2; ++c) acc = __builtin_amdgcn_mfma_f32_16x16x32_bf16(qf[mi][c][1], bf[ns][1][c], acc, 0, 0, 0); // mm
#pragma unroll
          for (int c = 0; c < 2; ++c) acc = __builtin_amdgcn_mfma_f32_16x16x32_bf16(qf[mi][c][0], bf[ns][2][c], acc, 0, 0, 0); // hl
#pragma unroll
          for (int c = 0; c < 2; ++c) acc = __builtin_amdgcn_mfma_f32_16x16x32_bf16(qf[mi][c][2], bf[ns][0][c], acc, 0, 0, 0); // lh
#pragma unroll
          for (int r = 0; r < 4; ++r) mx[mi][r] = fmaxf(mx[mi][r], acc[r]);
        }
      __builtin_amdgcn_s_setprio(0);
    }
  }

#pragma unroll
  for (int mi = 0; mi < 4; ++mi)
#pragma unroll
    for (int r = 0; r < 4; ++r) {
      float v = mx[mi][r];
      v = fmaxf(v, __shfl_xor(v, 1));
      v = fmaxf(v, __shfl_xor(v, 2));
      v = fmaxf(v, __shfl_xor(v, 4));
      v = fmaxf(v, __shfl_xor(v, 8));
      if (lr == 0)
        Mp[ks*32768 + bh*2048 + qt*256 + w*64 + mi*16 + lg*4 + r] = v;
    }
}

// ---------------------------------------------------------------- fused M-finalize + top-40 via radix-select
__global__ __launch_bounds__(256) void topk_kernel(const float* __restrict__ qp,
                                                   const float* __restrict__ ksum,
                                                   const float* __restrict__ Mp,
                                                   int* __restrict__ Mtop) {
  __shared__ float ks_s[64];
  __shared__ unsigned hist[256];
  __shared__ int wsum[4];
  __shared__ unsigned bitmap[64];
  __shared__ unsigned long long comb[NU];
  __shared__ int s_sel, s_rem, s_cnt;
  const int bh = blockIdx.x;
  const int b = bh >> 3, h = bh & 7;
  const int t = threadIdx.x;
  if (t < 64) ks_s[t] = ksum[bh*64 + t];
  __syncthreads();

  unsigned mykey[8];
#pragma unroll
  for (int c = 0; c < 8; ++c) {
    const int qi = c * 256 + t;
    const float* qrow = qp + (size_t)b*BHD + (size_t)h*QHS + (size_t)qi * 64;
    float dot = 0.f;
#pragma unroll
    for (int cc = 0; cc < 16; ++cc) {
      float4 q4 = ld4(qrow + 4 * cc);
      dot += q4.x * ks_s[4*cc + 0];
      dot += q4.y * ks_s[4*cc + 1];
      dot += q4.z * ks_s[4*cc + 2];
      dot += q4.w * ks_s[4*cc + 3];
    }
    const float mx2 = fmaxf(fmaxf(Mp[bh*2048 + qi], Mp[32768 + bh*2048 + qi]),
                            fmaxf(Mp[65536 + bh*2048 + qi], Mp[98304 + bh*2048 + qi]));
    const float m = mx2 - dot * (1.0f/2048.0f);
    const unsigned u = __float_as_uint(m);
    mykey[c] = (u >> 31) ? ~u : (u | 0x80000000u);
  }

  unsigned prefMask = 0u, prefVal = 0u;
  int rem = NU;
  for (int shift = 24; shift >= 0; shift -= 8) {
    hist[t] = 0;
    __syncthreads();
#pragma unroll
    for (int c = 0; c < 8; ++c) {
      const unsigned key = mykey[c];
      if ((key & prefMask) == prefVal)
        atomicAdd(&hist[(key >> shift) & 255], 1u);
    }
    __syncthreads();
    const int binc = (int)hist[t];
    int inc = binc;
#pragma unroll
    for (int off = 1; off < 64; off <<= 1) {
      const int nb = __shfl_up(inc, off);
      if ((t & 63) >= off) inc += nb;
    }
    if ((t & 63) == 63) wsum[t >> 6] = inc;
    __syncthreads();
    int wadd = 0;
    for (int w2 = 0; w2 < (t >> 6); ++w2) wadd += wsum[w2];
    const int incl = inc + wadd;
    const int excl = incl - binc;
    if (excl < rem && rem <= incl) { s_sel = t; s_rem = rem - excl; }
    __syncthreads();
    prefVal |= ((unsigned)s_sel) << shift;
    prefMask |= 0xFFu << shift;
    rem = s_rem;
    __syncthreads();
  }
  const unsigned T = prefVal;

  if (t < 64) bitmap[t] = 0;
  if (t == 0) s_cnt = 0;
  __syncthreads();
#pragma unroll
  for (int c = 0; c < 8; ++c) {
    const unsigned key = mykey[c];
    const int qi = c * 256 + t;
    if (key < T) {
      const int pos = atomicAdd(&s_cnt, 1);
      comb[pos] = ((unsigned long long)key << 11) | (unsigned)qi;
    } else if (key == T) {
      atomicOr(&bitmap[qi >> 5], 1u << (qi & 31));
    }
  }
  __syncthreads();
  if (t == 0) {
    int need = rem, cpos = s_cnt;
    for (int wd = 0; wd < 64 && need > 0; ++wd) {
      unsigned bits = bitmap[wd];
      while (bits && need > 0) {
        const int bit = __ffs(bits) - 1;
        bits &= bits - 1;
        comb[cpos++] = ((unsigned long long)T << 11) | (unsigned)(wd*32 + bit);
        --need;
      }
    }
  }
  __syncthreads();

  if (t < 64) {
    const unsigned long long mine = (t < NU) ? comb[t] : ~0ULL;
    int rank = 0;
#pragma unroll
    for (int step = 1; step < 64; ++step) {
      const unsigned long long other = __shfl(mine, (t + step) & 63);
      rank += (other < mine) ? 1 : 0;
    }
    if (t < NU) Mtop[bh*NU + rank] = (int)(mine & 0x7FFu);
  }
}

// ---------------------------------------------------------------- flash partials over 128-key slabs
__global__ __launch_bounds__(256) void flash_partial(const float* __restrict__ qp,
                                                     const float* __restrict__ kp,
                                                     const float* __restrict__ vp,
                                                     const int* __restrict__ Mtop,
                                                     float* __restrict__ pm,
                                                     float* __restrict__ pl,
                                                     float* __restrict__ pacc) {
  __shared__ float qr[NU][65];
  __shared__ float kv[64][65];
  __shared__ float sl[NU][65];
  __shared__ float ms[NU], ls[NU], fs[NU];
  const int bid = blockIdx.x;
  const int bh = bid >> 4, kt = bid & 15;
  const int b = bh >> 3, h = bh & 7;
  const int t = threadIdx.x;
  const int g = t >> 6, j = t & 63;
  const int r4 = t >> 2, sub = t & 3;

  {
    const float* qbase = qp + (size_t)b*BHD + (size_t)h*QHS;
#pragma unroll
    for (int r = 0; r < 10; ++r) {
      const int q = g*10 + r;
      qr[q][j] = qbase[(size_t)Mtop[bh*NU + q]*64 + j];
    }
  }
  if (t < NU) { ms[t] = -INFINITY; ls[t] = 0.f; }
  float acc[10];
#pragma unroll
  for (int r = 0; r < 10; ++r) acc[r] = 0.f;

  const float* kbase = kp + (size_t)b*BHD + h*DH;
  const float* vbase = vp + (size_t)b*BHD + h*DH;
  const int srow = t >> 2, scb = (t & 3)*16;

  for (int st = 0; st < 2; ++st) {
    const int kb = kt*128 + st*64;
    __syncthreads();
    {
      const float* src = kbase + (size_t)(kb + srow)*512 + scb;
#pragma unroll
      for (int i = 0; i < 4; ++i) {
        float4 v = ld4(src + 4*i);
        kv[srow][scb + 4*i + 0] = v.x;
        kv[srow][scb + 4*i + 1] = v.y;
        kv[srow][scb + 4*i + 2] = v.z;
        kv[srow][scb + 4*i + 3] = v.w;
      }
    }
    __syncthreads();
    {
      float sv[10];
#pragma unroll
      for (int r = 0; r < 10; ++r) {
        const int q = g*10 + r;
        float s = 0.f;
#pragma unroll 8
        for (int jj = 0; jj < 64; ++jj) s += qr[q][jj]*kv[j][jj];
        sv[r] = s * 0.125f;
      }
#pragma unroll
      for (int r = 0; r < 10; ++r) sl[g*10 + r][j] = sv[r];
    }
    __syncthreads();
    float4 vst[4];
    {
      const float* src = vbase + (size_t)(kb + srow)*512 + scb;
#pragma unroll
      for (int i = 0; i < 4; ++i) vst[i] = ld4(src + 4*i);
    }
    if (r4 < NU) {
      float tm = -INFINITY;
#pragma unroll
      for (int c = 0; c < 16; ++c) tm = fmaxf(tm, sl[r4][sub*16 + c]);
      tm = fmaxf(tm, __shfl_xor(tm, 1));
      tm = fmaxf(tm, __shfl_xor(tm, 2));
      const float nm = fmaxf(ms[r4], tm);
      if (sub == 0) { fs[r4] = expf(ms[r4] - nm); ms[r4] = nm; }
    }
    __syncthreads();
    {
#pragma unroll
      for (int r = 0; r < 10; ++r) {
        const int q = g*10 + r;
        acc[r] *= fs[q];
        sl[q][j] = expf(sl[q][j] - ms[q]);
      }
#pragma unroll
      for (int i = 0; i < 4; ++i) {
        kv[srow][scb + 4*i + 0] = vst[i].x;
        kv[srow][scb + 4*i + 1] = vst[i].y;
        kv[srow][scb + 4*i + 2] = vst[i].z;
        kv[srow][scb + 4*i + 3] = vst[i].w;
      }
    }
    __syncthreads();
    if (r4 < NU) {
      float s = 0.f;
#pragma unroll
      for (int c = 0; c < 16; ++c) s += sl[r4][sub*16 + c];
      s += __shfl_xor(s, 1);
      s += __shfl_xor(s, 2);
      if (sub == 0) ls[r4] = ls[r4]*fs[r4] + s;
    }
    {
#pragma unroll 4
      for (int kk = 0; kk < 64; ++kk) {
        const float vv = kv[kk][j];
#pragma unroll
        for (int r = 0; r < 10; ++r) acc[r] += sl[g*10 + r][kk]*vv;
      }
    }
  }
  __syncthreads();
  const size_t base = (size_t)(bh*16 + kt)*NU;
  if (t < NU) { pm[base + t] = ms[t]; pl[base + t] = ls[t]; }
#pragma unroll
  for (int r = 0; r < 10; ++r)
    pacc[(base + g*10 + r)*64 + j] = acc[r];
}

// ---------------------------------------------------------------- combine 16 partials, write outc (B,40,512)
__global__ __launch_bounds__(256) void flash_combine(const float* __restrict__ pm,
                                                     const float* __restrict__ pl,
                                                     const float* __restrict__ pacc,
                                                     float* __restrict__ outc) {
  const int t = threadIdx.x;
  const int qg = t >> 6, j = t & 63;
  const int bh = blockIdx.x / 10;
  const int q  = (blockIdx.x % 10)*4 + qg;
  const int b = bh >> 3, h = bh & 7;
  float m = -INFINITY;
#pragma unroll
  for (int kt = 0; kt < 16; ++kt) m = fmaxf(m, pm[(size_t)(bh*16 + kt)*NU + q]);
  float Lsum = 0.f, num = 0.f;
#pragma unroll
  for (int kt = 0; kt < 16; ++kt) {
    const size_t base = (size_t)(bh*16 + kt)*NU;
    const float w = expf(pm[base + q] - m);
    Lsum += w * pl[base + q];
    num  += w * pacc[(base + q)*64 + j];
  }
  outc[(size_t)(b*NU + q)*512 + h*64 + j] = num / Lsum;
}

// ---------------------------------------------------------------- Wo GEMM, split-k x4
__global__ __launch_bounds__(256) void wo_gemm(const float* __restrict__ outc,
                                               const float* __restrict__ Wo,
                                               float* __restrict__ pwo) {
  __shared__ __align__(16) float a_t[80][68];
  __shared__ __align__(16) float w_t[64][68];
  const int t = threadIdx.x;
  const int ty = t >> 4, tx = t & 15;
  const int nt = blockIdx.x, ks = blockIdx.y;
  float acc[5][4];
#pragma unroll
  for (int i = 0; i < 5; ++i)
#pragma unroll
    for (int j = 0; j < 4; ++j) acc[i][j] = 0.f;

  for (int c = 0; c < 2; ++c) {
    const int kb = ks*128 + c*64;
    __syncthreads();
#pragma unroll
    for (int i = 0; i < 20; ++i) {
      const int fi = t + 256*i;
      const int row = fi >> 6, col = fi & 63;
      a_t[row][col] = outc[(size_t)row*512 + kb + col];
    }
#pragma unroll
    for (int i = 0; i < 16; ++i) {
      const int fi = t + 256*i;
      const int row = fi >> 6, col = fi & 63;
      w_t[row][col] = Wo[(size_t)(nt*64 + row)*512 + kb + col];
    }
    __syncthreads();
    for (int gq = 0; gq < 16; ++gq) {
      float4 av[5], wv[4];
#pragma unroll
      for (int i = 0; i < 5; ++i) av[i] = *reinterpret_cast<const float4*>(&a_t[ty + 16*i][4*gq]);
#pragma unroll
      for (int j = 0; j < 4; ++j) wv[j] = *reinterpret_cast<const float4*>(&w_t[tx + 16*j][4*gq]);
#pragma unroll
      for (int i = 0; i < 5; ++i)
#pragma unroll
        for (int j = 0; j < 4; ++j) {
          acc[i][j] += av[i].x * wv[j].x;
          acc[i][j] += av[i].y * wv[j].y;
          acc[i][j] += av[i].z * wv[j].z;
          acc[i][j] += av[i].w * wv[j].w;
        }
    }
  }
#pragma unroll
  for (int i = 0; i < 5; ++i)
#pragma unroll
    for (int j = 0; j < 4; ++j)
      pwo[ks*40960 + (size_t)(ty + 16*i)*512 + nt*64 + tx + 16*j] = acc[i][j];
}

__global__ __launch_bounds__(256) void wo_combine(const float* __restrict__ pwo,
                                                  const float* __restrict__ bo,
                                                  float* __restrict__ out) {
  const int gi = blockIdx.x*256 + threadIdx.x;
  const float4* p = reinterpret_cast<const float4*>(pwo);
  const float4 a = p[gi], b4 = p[10240 + gi], c4 = p[20480 + gi], d4 = p[30720 + gi];
  const float4 bb = ld4(bo + 4*(gi & 127));
  float4 o;
  o.x = a.x + b4.x + c4.x + d4.x + bb.x;
  o.y = a.y + b4.y + c4.y + d4.y + bb.y;
  o.z = a.z + b4.z + c4.z + d4.z + bb.z;
  o.w = a.w + b4.w + c4.w + d4.w + bb.w;
  reinterpret_cast<float4*>(out)[gi] = o;
}

// ----------------------------------------------------------------
extern "C" void kernel_launch(void* const* d_in, const int* in_sizes, int n_in,
                              void* d_out, int out_size, void* d_ws, size_t ws_size,
                              hipStream_t stream) {
  const float* q  = (const float*)d_in[0];
  const float* k  = (const float*)d_in[1];
  const float* v  = (const float*)d_in[2];
  const float* Wq = (const float*)d_in[3];
  const float* bq = (const float*)d_in[4];
  const float* Wk = (const float*)d_in[5];
  const float* bk = (const float*)d_in[6];
  const float* Wv = (const float*)d_in[7];
  const float* bv = (const float*)d_in[8];
  const float* Wo = (const float*)d_in[9];
  const float* bo = (const float*)d_in[10];
  const int*  idx = (const int*)d_in[11];

  float* ws   = (float*)d_ws;
  float* qp   = ws;                        // 2,097,152
  float* kp   = ws + 2097152;              // 2,097,152
  float* vp   = ws + 4194304;              // 2,097,152
  float* ksum = ws + 6291456;              // 1,024
  int*   Mtop = (int*)(ws + 6292480);      // 640
  float* pm   = ws + 6293120;              // 10,240
  float* pl   = ws + 6303360;              // 10,240
  float* pacc = ws + 6313600;              // 655,360
  float* outc = ws + 6968960;              // 40,960  (end 7,009,920)
  // time-disjoint aliases:
  float* Mp   = pm;                        // 131,072 needed (4 ks-slices); dead before flash_partial
  float* pwo  = pm;                        // written after flash_combine reads pm/pl/pacc
  unsigned short* wsp = (unsigned short*)(ws + 6291456);  // live only during wsplit+proj

  const dim3 blk(256);
  const bool bigws = (ws_size >= (size_t)7471104 * 4);   // 3-mat W-split extends ws to 29.9 MB
  if (bigws) {
    wsplit<<<dim3(32, 3), blk, 0, stream>>>(Wq, Wk, Wv, wsp, -1);
    proj_mfma2<<<dim3(32, 4, 3), blk, 0, stream>>>(q, k, v, wsp, bq, bk, bv, qp, kp, vp, -1);
  } else {
    for (int m = 0; m < 3; ++m) {        // sequential per-mat fallback (identical numerics)
      wsplit<<<dim3(32, 1), blk, 0, stream>>>(Wq, Wk, Wv, wsp, m);
      proj_mfma2<<<dim3(32, 4, 1), blk, 0, stream>>>(q, k, v, wsp, bq, bk, bv, qp, kp, vp, m);
    }
  }
  ksum_kernel<<<dim3(16), dim3(1024), 0, stream>>>(kp, idx, ksum);
  m_kernel<<<dim3(512), blk, 0, stream>>>(qp, kp, idx, Mp);
  topk_kernel<<<dim3(16), blk, 0, stream>>>(qp, ksum, Mp, Mtop);
  flash_partial<<<dim3(256), blk, 0, stream>>>(qp, kp, vp, Mtop, pm, pl, pacc);
  flash_combine<<<dim3(160), blk, 0, stream>>>(pm, pl, pacc, outc);
  wo_gemm<<<dim3(8, 4), blk, 0, stream>>>(outc, Wo, pwo);
  wo_combine<<<dim3(40), blk, 0, stream>>>(pwo, bo, (float*)d_out);
}